// Round 10
// baseline (10737.230 us; speedup 1.0000x reference)
//
#include <hip/hip_runtime.h>
#include <cstdint>
#include <cstddef>

// ====================================================================
// PyroSimpleSpeakerListenerLSTM — Round 10.
// THE FIX: log-space gamma boost is log1p(-u)/alpha (JAX computes the
// exponential variate as -log1p(-U) to avoid log(0)), NOT log(u)/alpha.
// Config: partitionable threefry (modern default) + f32 sampling.
// Kernels _r10.
// ====================================================================

namespace {

constexpr int MZ = 512;
constexpr int EMB = 256;
constexpr int H = 512;
constexpr int SL = 32;
constexpr int BT = 16;
constexpr int AR = 64;
constexpr int GG = 4 * H;
constexpr int RD = BT * MZ;

struct KK { unsigned a, b; };

__host__ __device__ constexpr unsigned rotl32(unsigned v, int r) {
  return (v << r) | (v >> (32 - r));
}

__host__ __device__ constexpr KK tf(unsigned k0, unsigned k1, unsigned x0, unsigned x1) {
  unsigned k2 = k0 ^ k1 ^ 0x1BD11BDAu;
  x0 += k0; x1 += k1;
  x0 += x1; x1 = rotl32(x1,13); x1 ^= x0;
  x0 += x1; x1 = rotl32(x1,15); x1 ^= x0;
  x0 += x1; x1 = rotl32(x1,26); x1 ^= x0;
  x0 += x1; x1 = rotl32(x1, 6); x1 ^= x0;
  x0 += k1; x1 += k2 + 1u;
  x0 += x1; x1 = rotl32(x1,17); x1 ^= x0;
  x0 += x1; x1 = rotl32(x1,29); x1 ^= x0;
  x0 += x1; x1 = rotl32(x1,16); x1 ^= x0;
  x0 += x1; x1 = rotl32(x1,24); x1 ^= x0;
  x0 += k2; x1 += k0 + 2u;
  x0 += x1; x1 = rotl32(x1,13); x1 ^= x0;
  x0 += x1; x1 = rotl32(x1,15); x1 ^= x0;
  x0 += x1; x1 = rotl32(x1,26); x1 ^= x0;
  x0 += x1; x1 = rotl32(x1, 6); x1 ^= x0;
  x0 += k0; x1 += k1 + 3u;
  x0 += x1; x1 = rotl32(x1,17); x1 ^= x0;
  x0 += x1; x1 = rotl32(x1,29); x1 ^= x0;
  x0 += x1; x1 = rotl32(x1,16); x1 ^= x0;
  x0 += x1; x1 = rotl32(x1,24); x1 ^= x0;
  x0 += k1; x1 += k2 + 4u;
  x0 += x1; x1 = rotl32(x1,13); x1 ^= x0;
  x0 += x1; x1 = rotl32(x1,15); x1 ^= x0;
  x0 += x1; x1 = rotl32(x1,26); x1 ^= x0;
  x0 += x1; x1 = rotl32(x1, 6); x1 ^= x0;
  x0 += k2; x1 += k0 + 5u;
  return KK{x0, x1};
}

constexpr KK KEYA = tf(0u, 42u, 0u, 0u);
constexpr KK KEYB = tf(0u, 42u, 0u, 1u);

__device__ __forceinline__ void split2(KK k, KK& o0, KK& o1) {
  o0 = tf(k.a, k.b, 0u, 0u); o1 = tf(k.a, k.b, 0u, 1u);
}

__device__ __forceinline__ void split3(KK k, KK& o0, KK& o1, KK& o2) {
  o0 = tf(k.a, k.b, 0u, 0u); o1 = tf(k.a, k.b, 0u, 1u); o2 = tf(k.a, k.b, 0u, 2u);
}

__device__ __forceinline__ KK elem_key(KK gk, unsigned j) {
  return tf(gk.a, gk.b, 0u, j);
}

__device__ __forceinline__ unsigned rb32(KK k) {
  KK r = tf(k.a, k.b, 0u, 0u);
  return r.a ^ r.b;
}

__device__ __forceinline__ float u01_from_bits(unsigned bits) {
  return __uint_as_float(0x3F800000u | (bits >> 9)) - 1.0f;
}
__device__ __forceinline__ float uniform01(KK k) {
  return u01_from_bits(rb32(k));
}

__device__ float erfinv_xla(float x) {
  float xx = __fmul_rn(x, x);
  float w = -log1pf(-xx);
  float p;
  if (w < 5.0f) {
    w = __fsub_rn(w, 2.5f);
    p = 2.81022636e-08f;
    p = __fadd_rn(3.43273939e-07f, __fmul_rn(p, w));
    p = __fadd_rn(-3.5233877e-06f, __fmul_rn(p, w));
    p = __fadd_rn(-4.39150654e-06f, __fmul_rn(p, w));
    p = __fadd_rn(0.00021858087f, __fmul_rn(p, w));
    p = __fadd_rn(-0.00125372503f, __fmul_rn(p, w));
    p = __fadd_rn(-0.00417768164f, __fmul_rn(p, w));
    p = __fadd_rn(0.246640727f, __fmul_rn(p, w));
    p = __fadd_rn(1.50140941f, __fmul_rn(p, w));
  } else {
    w = __fsub_rn(__fsqrt_rn(w), 3.0f);
    p = -0.000200214257f;
    p = __fadd_rn(0.000100950558f, __fmul_rn(p, w));
    p = __fadd_rn(0.00134934322f, __fmul_rn(p, w));
    p = __fadd_rn(-0.00367342844f, __fmul_rn(p, w));
    p = __fadd_rn(0.00573950773f, __fmul_rn(p, w));
    p = __fadd_rn(-0.0076224613f, __fmul_rn(p, w));
    p = __fadd_rn(0.00943887047f, __fmul_rn(p, w));
    p = __fadd_rn(1.00167406f, __fmul_rn(p, w));
    p = __fadd_rn(2.83297682f, __fmul_rn(p, w));
  }
  return __fmul_rn(p, x);
}

__device__ __forceinline__ float normal_f(KK k) {
  float f = u01_from_bits(rb32(k));
  const float lo = __uint_as_float(0xBF7FFFFFu);
  float u = __fadd_rn(__fmul_rn(f, 2.0f), lo);
  u = fmaxf(lo, u);
  return __fmul_rn(__uint_as_float(0x3FB504F3u), erfinv_xla(u));
}

// jax _gamma_one (log_space=True):
//   boost subkey split first; loop: split3 -> (key, x_key, U_key);
//   inner: split2(x_key chain) -> normal; squeeze U<1-0.0331 X^2 or
//   log U < X/2 + d(1-V+logV); result log(d)+log(V) + log1p(-u_boost)/alpha.
__device__ float loggamma_one(KK ekey, float alpha_orig) {
  KK key, sub;
  split2(ekey, key, sub);
  float u_boost = uniform01(sub);
  const bool boost = (alpha_orig >= 1.0f);
  const float al = boost ? alpha_orig : __fadd_rn(alpha_orig, 1.0f);
  const float third = (float)(1.0 / 3.0);
  const float d = __fsub_rn(al, third);
  const float c = __fdiv_rn(third, __fsqrt_rn(d));
  float X, V;
  for (;;) {
    KK nk, xk, uk;
    split3(key, nk, xk, uk);
    key = nk;
    float x, v;
    KK kk = xk;
    do {
      KK k2, ns;
      split2(kk, k2, ns);
      kk = k2;
      x = normal_f(ns);
      v = __fadd_rn(1.0f, __fmul_rn(x, c));
    } while (v <= 0.0f);
    X = __fmul_rn(x, x);
    V = __fmul_rn(__fmul_rn(v, v), v);
    float U = uniform01(uk);
    float sq = __fsub_rn(1.0f, __fmul_rn(0.0331f, __fmul_rn(X, X)));
    if (U < sq) break;
    float rhs = __fadd_rn(__fmul_rn(0.5f, X),
                          __fmul_rn(d, __fadd_rn(__fsub_rn(1.0f, V), logf(V))));
    if (logf(U) < rhs) break;
  }
  float ls = __fadd_rn(logf(d), logf(V));
  if (!boost)   // THE FIX: Exponential computed as -log1p(-U); boost = log1p(-u)/alpha
    ls = __fadd_rn(ls, __fdiv_rn(log1pf(-u_boost), alpha_orig));
  return ls;
}

__device__ __forceinline__ float sigm(float x) { return 1.0f / (1.0f + expf(-x)); }

} // namespace

// ----------------------------- kernels ------------------------------

__global__ __launch_bounds__(256) void fill_sentinel_r10(float* o, int n) {
  int i = blockIdx.x * 256 + threadIdx.x;
  if (i < n) o[i] = 12345.0f;
}

__global__ __launch_bounds__(256) void init_states_r10(const float* __restrict__ encI,
                                                       const float* __restrict__ decI,
                                                       float* __restrict__ hE, float* __restrict__ cE,
                                                       float* __restrict__ hD, float* __restrict__ cD) {
  int idx = blockIdx.x * 256 + threadIdx.x;
  int u = idx & (H - 1);
  if (idx < MZ * H) { hE[idx] = encI[u]; cE[idx] = encI[H + u]; }
  hD[idx] = decI[u]; cD[idx] = decI[H + u];
}

template <int MODE>
__global__ __launch_bounds__(256) void gemm_abt_r10(const float* __restrict__ A,
                                                    const float* __restrict__ B,
                                                    float* __restrict__ C,
                                                    const float* __restrict__ X1,
                                                    const float* __restrict__ X2,
                                                    int M, int N, int K) {
  __shared__ float As[16][68];
  __shared__ float Bs[16][68];
  int tid = threadIdx.x;
  int tx = tid & 15, ty = tid >> 4;
  int n0 = blockIdx.x * 64, m0 = blockIdx.y * 64;
  int lr = tid >> 2, lk4 = (tid & 3) * 4;
  float acc[4][4] = {};
  for (int k0 = 0; k0 < K; k0 += 16) {
    float4 a4 = *reinterpret_cast<const float4*>(A + (size_t)(m0 + lr) * K + k0 + lk4);
    float4 b4 = *reinterpret_cast<const float4*>(B + (size_t)(n0 + lr) * K + k0 + lk4);
    __syncthreads();
    As[lk4 + 0][lr] = a4.x; As[lk4 + 1][lr] = a4.y; As[lk4 + 2][lr] = a4.z; As[lk4 + 3][lr] = a4.w;
    Bs[lk4 + 0][lr] = b4.x; Bs[lk4 + 1][lr] = b4.y; Bs[lk4 + 2][lr] = b4.z; Bs[lk4 + 3][lr] = b4.w;
    __syncthreads();
#pragma unroll
    for (int k = 0; k < 16; ++k) {
      float av[4], bv[4];
#pragma unroll
      for (int i = 0; i < 4; ++i) av[i] = As[k][ty * 4 + i];
#pragma unroll
      for (int j = 0; j < 4; ++j) bv[j] = Bs[k][tx * 4 + j];
#pragma unroll
      for (int i = 0; i < 4; ++i)
#pragma unroll
        for (int j = 0; j < 4; ++j) acc[i][j] = fmaf(av[i], bv[j], acc[i][j]);
    }
  }
#pragma unroll
  for (int i = 0; i < 4; ++i) {
    int m = m0 + ty * 4 + i;
#pragma unroll
    for (int j = 0; j < 4; ++j) {
      int n = n0 + tx * 4 + j;
      float v = acc[i][j];
      if (MODE == 1) v += X1[n] + X2[n];
      if (MODE == 2) v += X1[(size_t)m * N + n];
      C[(size_t)m * N + n] = v;
    }
  }
}

__global__ __launch_bounds__(256) void gemm_dec_r10(const float* __restrict__ A1,
                                                    const float* __restrict__ B1,
                                                    const float* __restrict__ A2,
                                                    const float* __restrict__ B2,
                                                    const float* __restrict__ b1,
                                                    const float* __restrict__ b2,
                                                    float* __restrict__ C) {
  __shared__ float As[16][68];
  __shared__ float Bs[16][68];
  int tid = threadIdx.x;
  int tx = tid & 15, ty = tid >> 4;
  int n0 = blockIdx.x * 64, m0 = blockIdx.y * 64;
  int lr = tid >> 2, lk4 = (tid & 3) * 4;
  float acc[4][4] = {};
  for (int phase = 0; phase < 2; ++phase) {
    const float* A = phase ? A2 : A1;
    const float* B = phase ? B2 : B1;
    const int K = phase ? H : AR;
    for (int k0 = 0; k0 < K; k0 += 16) {
      float4 a4 = *reinterpret_cast<const float4*>(A + (size_t)(m0 + lr) * K + k0 + lk4);
      float4 b4 = *reinterpret_cast<const float4*>(B + (size_t)(n0 + lr) * K + k0 + lk4);
      __syncthreads();
      As[lk4 + 0][lr] = a4.x; As[lk4 + 1][lr] = a4.y; As[lk4 + 2][lr] = a4.z; As[lk4 + 3][lr] = a4.w;
      Bs[lk4 + 0][lr] = b4.x; Bs[lk4 + 1][lr] = b4.y; Bs[lk4 + 2][lr] = b4.z; Bs[lk4 + 3][lr] = b4.w;
      __syncthreads();
#pragma unroll
      for (int k = 0; k < 16; ++k) {
        float av[4], bv[4];
#pragma unroll
        for (int i = 0; i < 4; ++i) av[i] = As[k][ty * 4 + i];
#pragma unroll
        for (int j = 0; j < 4; ++j) bv[j] = Bs[k][tx * 4 + j];
#pragma unroll
        for (int i = 0; i < 4; ++i)
#pragma unroll
          for (int j = 0; j < 4; ++j) acc[i][j] = fmaf(av[i], bv[j], acc[i][j]);
      }
    }
  }
#pragma unroll
  for (int i = 0; i < 4; ++i) {
    int m = m0 + ty * 4 + i;
#pragma unroll
    for (int j = 0; j < 4; ++j) {
      int n = n0 + tx * 4 + j;
      C[(size_t)m * GG + n] = acc[i][j] + b1[n] + b2[n];
    }
  }
}

template <int EPI>
__global__ __launch_bounds__(256) void gemm_ab_r10(const float* __restrict__ A,
                                                   const float* __restrict__ B,
                                                   float* __restrict__ C0,
                                                   float* __restrict__ C1,
                                                   int M, int N, int K) {
  __shared__ float As[16][68];
  __shared__ float Bs[16][68];
  int tid = threadIdx.x;
  int tx = tid & 15, ty = tid >> 4;
  int n0 = blockIdx.x * 64, m0 = blockIdx.y * 64;
  int lr = tid >> 2, lk4 = (tid & 3) * 4;
  int bk = tid >> 4, bn4 = (tid & 15) * 4;
  float acc[4][4] = {};
  for (int k0 = 0; k0 < K; k0 += 16) {
    float4 a4 = *reinterpret_cast<const float4*>(A + (size_t)(m0 + lr) * K + k0 + lk4);
    float4 b4 = *reinterpret_cast<const float4*>(B + (size_t)(k0 + bk) * N + n0 + bn4);
    __syncthreads();
    As[lk4 + 0][lr] = a4.x; As[lk4 + 1][lr] = a4.y; As[lk4 + 2][lr] = a4.z; As[lk4 + 3][lr] = a4.w;
    *reinterpret_cast<float4*>(&Bs[bk][bn4]) = b4;
    __syncthreads();
#pragma unroll
    for (int k = 0; k < 16; ++k) {
      float av[4], bv[4];
#pragma unroll
      for (int i = 0; i < 4; ++i) av[i] = As[k][ty * 4 + i];
#pragma unroll
      for (int j = 0; j < 4; ++j) bv[j] = Bs[k][tx * 4 + j];
#pragma unroll
      for (int i = 0; i < 4; ++i)
#pragma unroll
        for (int j = 0; j < 4; ++j) acc[i][j] = fmaf(av[i], bv[j], acc[i][j]);
    }
  }
#pragma unroll
  for (int i = 0; i < 4; ++i) {
    size_t m = (size_t)(m0 + ty * 4 + i);
#pragma unroll
    for (int j = 0; j < 4; ++j) {
      int n = n0 + tx * 4 + j;
      float v = acc[i][j];
      if (EPI == 0) {
        C0[m * N + n] = v;
      } else {
        float sp = fmaxf(v, 0.0f) + log1pf(expf(-fabsf(v)));
        if (n & 1) C1[m * (N / 2) + (n >> 1)] = sp;
        else       C0[m * (N / 2) + (n >> 1)] = sp;
      }
    }
  }
}

__global__ __launch_bounds__(256) void lstm_update_r10(float* __restrict__ h, float* __restrict__ c,
                                                       const float* __restrict__ gates,
                                                       float* __restrict__ ysOut) {
  int idx = blockIdx.x * 256 + threadIdx.x;
  int r = idx >> 9, u = idx & (H - 1);
  const float* g = gates + (size_t)r * GG;
  float gi = g[u], gf = g[u + H], gg = g[u + 2 * H], go = g[u + 3 * H];
  float cn = sigm(gf) * c[idx] + sigm(gi) * tanhf(gg);
  float hn = sigm(go) * tanhf(cn);
  c[idx] = cn; h[idx] = hn;
  if (ysOut) ysOut[idx] = hn;
}

__global__ __launch_bounds__(256) void sample_beta_r10(const float* __restrict__ alphaA,
                                                       const float* __restrict__ betaA,
                                                       float* __restrict__ sig, int s) {
  unsigned idx = blockIdx.x * 256 + threadIdx.x;
  unsigned r = idx >> 6;
  unsigned j = idx & 63u;
  unsigned b = r >> 9;
  unsigned m = r & 511u;
  size_t ab = ((size_t)s * MZ + m) * AR + j;
  float alpha = alphaA[ab];
  float beta = betaA[ab];
  unsigned jl = ((b * 32u + (unsigned)s) * 512u + m) * 64u + j;
  float lga = loggamma_one(elem_key(KEYA, jl), alpha);
  float lgb = loggamma_one(elem_key(KEYB, jl), beta);
  float lm = fmaxf(lga, lgb);
  float ea = expf(__fsub_rn(lga, lm));
  float eb = expf(__fsub_rn(lgb, lm));
  sig[idx] = __fdiv_rn(ea, __fadd_rn(ea, eb));
}

__global__ __launch_bounds__(256) void softmax_rows_r10(const float* __restrict__ L,
                                                        float* __restrict__ O) {
  __shared__ float red[8];
  int r = blockIdx.x;
  const float* row = L + (size_t)r * H;
  int t = threadIdx.x;
  float a = row[t], b = row[t + 256];
  float m = fmaxf(a, b);
#pragma unroll
  for (int o = 1; o < 64; o <<= 1) m = fmaxf(m, __shfl_xor(m, o));
  if ((t & 63) == 0) red[t >> 6] = m;
  __syncthreads();
  m = fmaxf(fmaxf(red[0], red[1]), fmaxf(red[2], red[3]));
  float e0 = expf(a - m), e1 = expf(b - m);
  float s = e0 + e1;
#pragma unroll
  for (int o = 1; o < 64; o <<= 1) s += __shfl_xor(s, o);
  if ((t & 63) == 0) red[4 + (t >> 6)] = s;
  __syncthreads();
  s = red[4] + red[5] + red[6] + red[7];
  O[(size_t)r * H + t] = e0 / s;
  O[(size_t)r * H + t + 256] = e1 / s;
}

// ----------------------------- launcher -----------------------------

extern "C" void kernel_launch(void* const* d_in, const int* in_sizes, int n_in,
                              void* d_out, int out_size, void* d_ws, size_t ws_size,
                              hipStream_t stream) {
  (void)in_sizes; (void)n_in;
  const float* embedding = (const float*)d_in[2];
  const float* eWih = (const float*)d_in[3];
  const float* eWhh = (const float*)d_in[4];
  const float* ebih = (const float*)d_in[5];
  const float* ebhh = (const float*)d_in[6];
  const float* eInit = (const float*)d_in[7];
  const float* dWih = (const float*)d_in[8];
  const float* dWhh = (const float*)d_in[9];
  const float* dbih = (const float*)d_in[10];
  const float* dbhh = (const float*)d_in[11];
  const float* dInit = (const float*)d_in[12];
  const float* Wp = (const float*)d_in[13];
  const float* Wo = (const float*)d_in[14];
  float* out = (float*)d_out;
  float* w = (float*)d_ws;

  size_t o = 0;
  float* xW     = w + o; o += (size_t)MZ * GG;
  float* hE     = w + o; o += (size_t)MZ * H;
  float* cE     = w + o; o += (size_t)MZ * H;
  float* ys     = w + o; o += (size_t)SL * MZ * H;
  float* alphaA = w + o; o += (size_t)SL * MZ * AR;
  float* betaA  = w + o; o += (size_t)SL * MZ * AR;
  float* hD     = w + o; o += (size_t)RD * H;
  float* cD     = w + o; o += (size_t)RD * H;
  float* sig    = w + o; o += (size_t)RD * AR;
  float* gates  = w + o; o += (size_t)RD * GG;
  if (ws_size < o * sizeof(float)) {
    fill_sentinel_r10<<<(out_size + 255) / 256, 256, 0, stream>>>(out, out_size);
    return;
  }
  float* logits = gates;

  init_states_r10<<<(RD * H) / 256, 256, 0, stream>>>(eInit, dInit, hE, cE, hD, cD);

  gemm_abt_r10<1><<<dim3(GG / 64, MZ / 64), 256, 0, stream>>>(embedding, eWih, xW, ebih, ebhh, MZ, GG, EMB);

  for (int s = 0; s < SL; ++s) {
    gemm_abt_r10<2><<<dim3(GG / 64, MZ / 64), 256, 0, stream>>>(hE, eWhh, gates, xW, nullptr, MZ, GG, H);
    lstm_update_r10<<<(MZ * H) / 256, 256, 0, stream>>>(hE, cE, gates, ys + (size_t)s * MZ * H);
  }

  gemm_ab_r10<1><<<dim3(128 / 64, (SL * MZ) / 64), 256, 0, stream>>>(ys, Wp, alphaA, betaA, SL * MZ, 128, H);

  for (int s = 0; s < SL; ++s) {
    sample_beta_r10<<<(RD * AR) / 256, 256, 0, stream>>>(alphaA, betaA, sig, s);
    gemm_dec_r10<<<dim3(GG / 64, RD / 64), 256, 0, stream>>>(sig, dWih, hD, dWhh, dbih, dbhh, gates);
    lstm_update_r10<<<(RD * H) / 256, 256, 0, stream>>>(hD, cD, gates, nullptr);
  }

  gemm_ab_r10<0><<<dim3(H / 64, RD / 64), 256, 0, stream>>>(hD, Wo, logits, nullptr, RD, H, H);
  softmax_rows_r10<<<RD, 256, 0, stream>>>(logits, out);
}

// Round 11
// 9995.592 us; speedup vs baseline: 1.0742x; 1.0742x over previous
//
#include <hip/hip_runtime.h>
#include <cstdint>
#include <cstddef>

// ====================================================================
// PyroSimpleSpeakerListenerLSTM — Round 11 (first perf round).
// r10 passed (absmax 1.5e-5). gemm_dec = 8ms of 10.7ms, VALU-bound at
// 49% of fp32 peak with 4x4/thread. This round: 128x128 tile, 8x8 acc
// per thread (FMA:ds_read 64:4 vs 16:2) -> target ~88% VALUBusy.
// Same accumulation order as r10 => numerically identical output.
// Kernels _r11.
// ====================================================================

namespace {

constexpr int MZ = 512;
constexpr int EMB = 256;
constexpr int H = 512;
constexpr int SL = 32;
constexpr int BT = 16;
constexpr int AR = 64;
constexpr int GG = 4 * H;
constexpr int RD = BT * MZ;

struct KK { unsigned a, b; };

__host__ __device__ constexpr unsigned rotl32(unsigned v, int r) {
  return (v << r) | (v >> (32 - r));
}

__host__ __device__ constexpr KK tf(unsigned k0, unsigned k1, unsigned x0, unsigned x1) {
  unsigned k2 = k0 ^ k1 ^ 0x1BD11BDAu;
  x0 += k0; x1 += k1;
  x0 += x1; x1 = rotl32(x1,13); x1 ^= x0;
  x0 += x1; x1 = rotl32(x1,15); x1 ^= x0;
  x0 += x1; x1 = rotl32(x1,26); x1 ^= x0;
  x0 += x1; x1 = rotl32(x1, 6); x1 ^= x0;
  x0 += k1; x1 += k2 + 1u;
  x0 += x1; x1 = rotl32(x1,17); x1 ^= x0;
  x0 += x1; x1 = rotl32(x1,29); x1 ^= x0;
  x0 += x1; x1 = rotl32(x1,16); x1 ^= x0;
  x0 += x1; x1 = rotl32(x1,24); x1 ^= x0;
  x0 += k2; x1 += k0 + 2u;
  x0 += x1; x1 = rotl32(x1,13); x1 ^= x0;
  x0 += x1; x1 = rotl32(x1,15); x1 ^= x0;
  x0 += x1; x1 = rotl32(x1,26); x1 ^= x0;
  x0 += x1; x1 = rotl32(x1, 6); x1 ^= x0;
  x0 += k0; x1 += k1 + 3u;
  x0 += x1; x1 = rotl32(x1,17); x1 ^= x0;
  x0 += x1; x1 = rotl32(x1,29); x1 ^= x0;
  x0 += x1; x1 = rotl32(x1,16); x1 ^= x0;
  x0 += x1; x1 = rotl32(x1,24); x1 ^= x0;
  x0 += k1; x1 += k2 + 4u;
  x0 += x1; x1 = rotl32(x1,13); x1 ^= x0;
  x0 += x1; x1 = rotl32(x1,15); x1 ^= x0;
  x0 += x1; x1 = rotl32(x1,26); x1 ^= x0;
  x0 += x1; x1 = rotl32(x1, 6); x1 ^= x0;
  x0 += k2; x1 += k0 + 5u;
  return KK{x0, x1};
}

constexpr KK KEYA = tf(0u, 42u, 0u, 0u);
constexpr KK KEYB = tf(0u, 42u, 0u, 1u);

__device__ __forceinline__ void split2(KK k, KK& o0, KK& o1) {
  o0 = tf(k.a, k.b, 0u, 0u); o1 = tf(k.a, k.b, 0u, 1u);
}

__device__ __forceinline__ void split3(KK k, KK& o0, KK& o1, KK& o2) {
  o0 = tf(k.a, k.b, 0u, 0u); o1 = tf(k.a, k.b, 0u, 1u); o2 = tf(k.a, k.b, 0u, 2u);
}

__device__ __forceinline__ KK elem_key(KK gk, unsigned j) {
  return tf(gk.a, gk.b, 0u, j);
}

__device__ __forceinline__ unsigned rb32(KK k) {
  KK r = tf(k.a, k.b, 0u, 0u);
  return r.a ^ r.b;
}

__device__ __forceinline__ float u01_from_bits(unsigned bits) {
  return __uint_as_float(0x3F800000u | (bits >> 9)) - 1.0f;
}
__device__ __forceinline__ float uniform01(KK k) {
  return u01_from_bits(rb32(k));
}

__device__ float erfinv_xla(float x) {
  float xx = __fmul_rn(x, x);
  float w = -log1pf(-xx);
  float p;
  if (w < 5.0f) {
    w = __fsub_rn(w, 2.5f);
    p = 2.81022636e-08f;
    p = __fadd_rn(3.43273939e-07f, __fmul_rn(p, w));
    p = __fadd_rn(-3.5233877e-06f, __fmul_rn(p, w));
    p = __fadd_rn(-4.39150654e-06f, __fmul_rn(p, w));
    p = __fadd_rn(0.00021858087f, __fmul_rn(p, w));
    p = __fadd_rn(-0.00125372503f, __fmul_rn(p, w));
    p = __fadd_rn(-0.00417768164f, __fmul_rn(p, w));
    p = __fadd_rn(0.246640727f, __fmul_rn(p, w));
    p = __fadd_rn(1.50140941f, __fmul_rn(p, w));
  } else {
    w = __fsub_rn(__fsqrt_rn(w), 3.0f);
    p = -0.000200214257f;
    p = __fadd_rn(0.000100950558f, __fmul_rn(p, w));
    p = __fadd_rn(0.00134934322f, __fmul_rn(p, w));
    p = __fadd_rn(-0.00367342844f, __fmul_rn(p, w));
    p = __fadd_rn(0.00573950773f, __fmul_rn(p, w));
    p = __fadd_rn(-0.0076224613f, __fmul_rn(p, w));
    p = __fadd_rn(0.00943887047f, __fmul_rn(p, w));
    p = __fadd_rn(1.00167406f, __fmul_rn(p, w));
    p = __fadd_rn(2.83297682f, __fmul_rn(p, w));
  }
  return __fmul_rn(p, x);
}

__device__ __forceinline__ float normal_f(KK k) {
  float f = u01_from_bits(rb32(k));
  const float lo = __uint_as_float(0xBF7FFFFFu);
  float u = __fadd_rn(__fmul_rn(f, 2.0f), lo);
  u = fmaxf(lo, u);
  return __fmul_rn(__uint_as_float(0x3FB504F3u), erfinv_xla(u));
}

__device__ float loggamma_one(KK ekey, float alpha_orig) {
  KK key, sub;
  split2(ekey, key, sub);
  float u_boost = uniform01(sub);
  const bool boost = (alpha_orig >= 1.0f);
  const float al = boost ? alpha_orig : __fadd_rn(alpha_orig, 1.0f);
  const float third = (float)(1.0 / 3.0);
  const float d = __fsub_rn(al, third);
  const float c = __fdiv_rn(third, __fsqrt_rn(d));
  float X, V;
  for (;;) {
    KK nk, xk, uk;
    split3(key, nk, xk, uk);
    key = nk;
    float x, v;
    KK kk = xk;
    do {
      KK k2, ns;
      split2(kk, k2, ns);
      kk = k2;
      x = normal_f(ns);
      v = __fadd_rn(1.0f, __fmul_rn(x, c));
    } while (v <= 0.0f);
    X = __fmul_rn(x, x);
    V = __fmul_rn(__fmul_rn(v, v), v);
    float U = uniform01(uk);
    float sq = __fsub_rn(1.0f, __fmul_rn(0.0331f, __fmul_rn(X, X)));
    if (U < sq) break;
    float rhs = __fadd_rn(__fmul_rn(0.5f, X),
                          __fmul_rn(d, __fadd_rn(__fsub_rn(1.0f, V), logf(V))));
    if (logf(U) < rhs) break;
  }
  float ls = __fadd_rn(logf(d), logf(V));
  if (!boost)   // log-space boost: Exponential = -log1p(-U)
    ls = __fadd_rn(ls, __fdiv_rn(log1pf(-u_boost), alpha_orig));
  return ls;
}

__device__ __forceinline__ float sigm(float x) { return 1.0f / (1.0f + expf(-x)); }

} // namespace

// ----------------------------- kernels ------------------------------

__global__ __launch_bounds__(256) void fill_sentinel_r11(float* o, int n) {
  int i = blockIdx.x * 256 + threadIdx.x;
  if (i < n) o[i] = 12345.0f;
}

__global__ __launch_bounds__(256) void init_states_r11(const float* __restrict__ encI,
                                                       const float* __restrict__ decI,
                                                       float* __restrict__ hE, float* __restrict__ cE,
                                                       float* __restrict__ hD, float* __restrict__ cD) {
  int idx = blockIdx.x * 256 + threadIdx.x;
  int u = idx & (H - 1);
  if (idx < MZ * H) { hE[idx] = encI[u]; cE[idx] = encI[H + u]; }
  hD[idx] = decI[u]; cD[idx] = decI[H + u];
}

// --- encoder GEMM (unchanged structure, 64x64 tile; M=512 -> 256 blocks) ---
template <int MODE>
__global__ __launch_bounds__(256) void gemm_abt_r11(const float* __restrict__ A,
                                                    const float* __restrict__ B,
                                                    float* __restrict__ C,
                                                    const float* __restrict__ X1,
                                                    const float* __restrict__ X2,
                                                    int M, int N, int K) {
  __shared__ float As[16][68];
  __shared__ float Bs[16][68];
  int tid = threadIdx.x;
  int tx = tid & 15, ty = tid >> 4;
  int n0 = blockIdx.x * 64, m0 = blockIdx.y * 64;
  int lr = tid >> 2, lk4 = (tid & 3) * 4;
  float acc[4][4] = {};
  for (int k0 = 0; k0 < K; k0 += 16) {
    float4 a4 = *reinterpret_cast<const float4*>(A + (size_t)(m0 + lr) * K + k0 + lk4);
    float4 b4 = *reinterpret_cast<const float4*>(B + (size_t)(n0 + lr) * K + k0 + lk4);
    __syncthreads();
    As[lk4 + 0][lr] = a4.x; As[lk4 + 1][lr] = a4.y; As[lk4 + 2][lr] = a4.z; As[lk4 + 3][lr] = a4.w;
    Bs[lk4 + 0][lr] = b4.x; Bs[lk4 + 1][lr] = b4.y; Bs[lk4 + 2][lr] = b4.z; Bs[lk4 + 3][lr] = b4.w;
    __syncthreads();
#pragma unroll
    for (int k = 0; k < 16; ++k) {
      float av[4], bv[4];
#pragma unroll
      for (int i = 0; i < 4; ++i) av[i] = As[k][ty * 4 + i];
#pragma unroll
      for (int j = 0; j < 4; ++j) bv[j] = Bs[k][tx * 4 + j];
#pragma unroll
      for (int i = 0; i < 4; ++i)
#pragma unroll
        for (int j = 0; j < 4; ++j) acc[i][j] = fmaf(av[i], bv[j], acc[i][j]);
    }
  }
#pragma unroll
  for (int i = 0; i < 4; ++i) {
    int m = m0 + ty * 4 + i;
#pragma unroll
    for (int j = 0; j < 4; ++j) {
      int n = n0 + tx * 4 + j;
      float v = acc[i][j];
      if (MODE == 1) v += X1[n] + X2[n];
      if (MODE == 2) v += X1[(size_t)m * N + n];
      C[(size_t)m * N + n] = v;
    }
  }
}

// --- decoder fused gates GEMM: 128x128 tile, 8x8 per thread, Kstep=16 ---
// C[RD,GG] = A1[RD,64]@B1[GG,64]^T + A2[RD,512]@B2[GG,512]^T + b1[n]+b2[n]
__global__ __launch_bounds__(256) void gemm_dec128_r11(const float* __restrict__ A1,
                                                       const float* __restrict__ B1,
                                                       const float* __restrict__ A2,
                                                       const float* __restrict__ B2,
                                                       const float* __restrict__ b1,
                                                       const float* __restrict__ b2,
                                                       float* __restrict__ C) {
  __shared__ float As[16][132];
  __shared__ float Bs[16][132];
  int tid = threadIdx.x;
  int tx = tid & 15, ty = tid >> 4;      // 16x16 thread grid; 8x8 acc each
  int n0 = blockIdx.x * 128, m0 = blockIdx.y * 128;
  int row = tid >> 2;                    // 0..63 (two halves: row, row+64)
  int kc = (tid & 3) * 4;                // 0,4,8,12
  float acc[8][8] = {};
  for (int phase = 0; phase < 2; ++phase) {
    const float* A = phase ? A2 : A1;
    const float* B = phase ? B2 : B1;
    const int K = phase ? H : AR;
    for (int k0 = 0; k0 < K; k0 += 16) {
      float4 a0 = *reinterpret_cast<const float4*>(A + (size_t)(m0 + row) * K + k0 + kc);
      float4 a1 = *reinterpret_cast<const float4*>(A + (size_t)(m0 + 64 + row) * K + k0 + kc);
      float4 g0 = *reinterpret_cast<const float4*>(B + (size_t)(n0 + row) * K + k0 + kc);
      float4 g1 = *reinterpret_cast<const float4*>(B + (size_t)(n0 + 64 + row) * K + k0 + kc);
      __syncthreads();
      As[kc + 0][row] = a0.x; As[kc + 1][row] = a0.y; As[kc + 2][row] = a0.z; As[kc + 3][row] = a0.w;
      As[kc + 0][row + 64] = a1.x; As[kc + 1][row + 64] = a1.y; As[kc + 2][row + 64] = a1.z; As[kc + 3][row + 64] = a1.w;
      Bs[kc + 0][row] = g0.x; Bs[kc + 1][row] = g0.y; Bs[kc + 2][row] = g0.z; Bs[kc + 3][row] = g0.w;
      Bs[kc + 0][row + 64] = g1.x; Bs[kc + 1][row + 64] = g1.y; Bs[kc + 2][row + 64] = g1.z; Bs[kc + 3][row + 64] = g1.w;
      __syncthreads();
#pragma unroll
      for (int k = 0; k < 16; ++k) {
        float av[8], bv[8];
#pragma unroll
        for (int i = 0; i < 8; ++i) av[i] = As[k][ty * 8 + i];
#pragma unroll
        for (int j = 0; j < 8; ++j) bv[j] = Bs[k][tx * 8 + j];
#pragma unroll
        for (int i = 0; i < 8; ++i)
#pragma unroll
          for (int j = 0; j < 8; ++j) acc[i][j] = fmaf(av[i], bv[j], acc[i][j]);
      }
    }
  }
#pragma unroll
  for (int i = 0; i < 8; ++i) {
    int m = m0 + ty * 8 + i;
#pragma unroll
    for (int j = 0; j < 8; ++j) {
      int n = n0 + tx * 8 + j;
      C[(size_t)m * GG + n] = acc[i][j] + b1[n] + b2[n];
    }
  }
}

// C[M,N] = A[M,K] @ B[K,N]. EPI 0: plain. EPI 1: softplus + even/odd split (N=128).
template <int EPI>
__global__ __launch_bounds__(256) void gemm_ab_r11(const float* __restrict__ A,
                                                   const float* __restrict__ B,
                                                   float* __restrict__ C0,
                                                   float* __restrict__ C1,
                                                   int M, int N, int K) {
  __shared__ float As[16][68];
  __shared__ float Bs[16][68];
  int tid = threadIdx.x;
  int tx = tid & 15, ty = tid >> 4;
  int n0 = blockIdx.x * 64, m0 = blockIdx.y * 64;
  int lr = tid >> 2, lk4 = (tid & 3) * 4;
  int bk = tid >> 4, bn4 = (tid & 15) * 4;
  float acc[4][4] = {};
  for (int k0 = 0; k0 < K; k0 += 16) {
    float4 a4 = *reinterpret_cast<const float4*>(A + (size_t)(m0 + lr) * K + k0 + lk4);
    float4 b4 = *reinterpret_cast<const float4*>(B + (size_t)(k0 + bk) * N + n0 + bn4);
    __syncthreads();
    As[lk4 + 0][lr] = a4.x; As[lk4 + 1][lr] = a4.y; As[lk4 + 2][lr] = a4.z; As[lk4 + 3][lr] = a4.w;
    *reinterpret_cast<float4*>(&Bs[bk][bn4]) = b4;
    __syncthreads();
#pragma unroll
    for (int k = 0; k < 16; ++k) {
      float av[4], bv[4];
#pragma unroll
      for (int i = 0; i < 4; ++i) av[i] = As[k][ty * 4 + i];
#pragma unroll
      for (int j = 0; j < 4; ++j) bv[j] = Bs[k][tx * 4 + j];
#pragma unroll
      for (int i = 0; i < 4; ++i)
#pragma unroll
        for (int j = 0; j < 4; ++j) acc[i][j] = fmaf(av[i], bv[j], acc[i][j]);
    }
  }
#pragma unroll
  for (int i = 0; i < 4; ++i) {
    size_t m = (size_t)(m0 + ty * 4 + i);
#pragma unroll
    for (int j = 0; j < 4; ++j) {
      int n = n0 + tx * 4 + j;
      float v = acc[i][j];
      if (EPI == 0) {
        C0[m * N + n] = v;
      } else {
        float sp = fmaxf(v, 0.0f) + log1pf(expf(-fabsf(v)));
        if (n & 1) C1[m * (N / 2) + (n >> 1)] = sp;
        else       C0[m * (N / 2) + (n >> 1)] = sp;
      }
    }
  }
}

__global__ __launch_bounds__(256) void lstm_update_r11(float* __restrict__ h, float* __restrict__ c,
                                                       const float* __restrict__ gates,
                                                       float* __restrict__ ysOut) {
  int idx = blockIdx.x * 256 + threadIdx.x;
  int r = idx >> 9, u = idx & (H - 1);
  const float* g = gates + (size_t)r * GG;
  float gi = g[u], gf = g[u + H], gg = g[u + 2 * H], go = g[u + 3 * H];
  float cn = sigm(gf) * c[idx] + sigm(gi) * tanhf(gg);
  float hn = sigm(go) * tanhf(cn);
  c[idx] = cn; h[idx] = hn;
  if (ysOut) ysOut[idx] = hn;
}

__global__ __launch_bounds__(256) void sample_beta_r11(const float* __restrict__ alphaA,
                                                       const float* __restrict__ betaA,
                                                       float* __restrict__ sig, int s) {
  unsigned idx = blockIdx.x * 256 + threadIdx.x;
  unsigned r = idx >> 6;
  unsigned j = idx & 63u;
  unsigned b = r >> 9;
  unsigned m = r & 511u;
  size_t ab = ((size_t)s * MZ + m) * AR + j;
  float alpha = alphaA[ab];
  float beta = betaA[ab];
  unsigned jl = ((b * 32u + (unsigned)s) * 512u + m) * 64u + j;
  float lga = loggamma_one(elem_key(KEYA, jl), alpha);
  float lgb = loggamma_one(elem_key(KEYB, jl), beta);
  float lm = fmaxf(lga, lgb);
  float ea = expf(__fsub_rn(lga, lm));
  float eb = expf(__fsub_rn(lgb, lm));
  sig[idx] = __fdiv_rn(ea, __fadd_rn(ea, eb));
}

__global__ __launch_bounds__(256) void softmax_rows_r11(const float* __restrict__ L,
                                                        float* __restrict__ O) {
  __shared__ float red[8];
  int r = blockIdx.x;
  const float* row = L + (size_t)r * H;
  int t = threadIdx.x;
  float a = row[t], b = row[t + 256];
  float m = fmaxf(a, b);
#pragma unroll
  for (int o = 1; o < 64; o <<= 1) m = fmaxf(m, __shfl_xor(m, o));
  if ((t & 63) == 0) red[t >> 6] = m;
  __syncthreads();
  m = fmaxf(fmaxf(red[0], red[1]), fmaxf(red[2], red[3]));
  float e0 = expf(a - m), e1 = expf(b - m);
  float s = e0 + e1;
#pragma unroll
  for (int o = 1; o < 64; o <<= 1) s += __shfl_xor(s, o);
  if ((t & 63) == 0) red[4 + (t >> 6)] = s;
  __syncthreads();
  s = red[4] + red[5] + red[6] + red[7];
  O[(size_t)r * H + t] = e0 / s;
  O[(size_t)r * H + t + 256] = e1 / s;
}

// ----------------------------- launcher -----------------------------

extern "C" void kernel_launch(void* const* d_in, const int* in_sizes, int n_in,
                              void* d_out, int out_size, void* d_ws, size_t ws_size,
                              hipStream_t stream) {
  (void)in_sizes; (void)n_in;
  const float* embedding = (const float*)d_in[2];
  const float* eWih = (const float*)d_in[3];
  const float* eWhh = (const float*)d_in[4];
  const float* ebih = (const float*)d_in[5];
  const float* ebhh = (const float*)d_in[6];
  const float* eInit = (const float*)d_in[7];
  const float* dWih = (const float*)d_in[8];
  const float* dWhh = (const float*)d_in[9];
  const float* dbih = (const float*)d_in[10];
  const float* dbhh = (const float*)d_in[11];
  const float* dInit = (const float*)d_in[12];
  const float* Wp = (const float*)d_in[13];
  const float* Wo = (const float*)d_in[14];
  float* out = (float*)d_out;
  float* w = (float*)d_ws;

  size_t o = 0;
  float* xW     = w + o; o += (size_t)MZ * GG;
  float* hE     = w + o; o += (size_t)MZ * H;
  float* cE     = w + o; o += (size_t)MZ * H;
  float* ys     = w + o; o += (size_t)SL * MZ * H;
  float* alphaA = w + o; o += (size_t)SL * MZ * AR;
  float* betaA  = w + o; o += (size_t)SL * MZ * AR;
  float* hD     = w + o; o += (size_t)RD * H;
  float* cD     = w + o; o += (size_t)RD * H;
  float* sig    = w + o; o += (size_t)RD * AR;
  float* gates  = w + o; o += (size_t)RD * GG;
  if (ws_size < o * sizeof(float)) {
    fill_sentinel_r11<<<(out_size + 255) / 256, 256, 0, stream>>>(out, out_size);
    return;
  }
  float* logits = gates;

  init_states_r11<<<(RD * H) / 256, 256, 0, stream>>>(eInit, dInit, hE, cE, hD, cD);

  gemm_abt_r11<1><<<dim3(GG / 64, MZ / 64), 256, 0, stream>>>(embedding, eWih, xW, ebih, ebhh, MZ, GG, EMB);

  for (int s = 0; s < SL; ++s) {
    gemm_abt_r11<2><<<dim3(GG / 64, MZ / 64), 256, 0, stream>>>(hE, eWhh, gates, xW, nullptr, MZ, GG, H);
    lstm_update_r11<<<(MZ * H) / 256, 256, 0, stream>>>(hE, cE, gates, ys + (size_t)s * MZ * H);
  }

  gemm_ab_r11<1><<<dim3(128 / 64, (SL * MZ) / 64), 256, 0, stream>>>(ys, Wp, alphaA, betaA, SL * MZ, 128, H);

  for (int s = 0; s < SL; ++s) {
    sample_beta_r11<<<(RD * AR) / 256, 256, 0, stream>>>(alphaA, betaA, sig, s);
    gemm_dec128_r11<<<dim3(GG / 128, RD / 128), 256, 0, stream>>>(sig, dWih, hD, dWhh, dbih, dbhh, gates);
    lstm_update_r11<<<(RD * H) / 256, 256, 0, stream>>>(hD, cD, gates, nullptr);
  }

  gemm_ab_r11<0><<<dim3(H / 64, RD / 64), 256, 0, stream>>>(hD, Wo, logits, nullptr, RD, H, H);
  softmax_rows_r11<<<RD, 256, 0, stream>>>(logits, out);
}

// Round 12
// 7403.486 us; speedup vs baseline: 1.4503x; 1.3501x over previous
//
#include <hip/hip_runtime.h>
#include <cstdint>
#include <cstddef>

// ====================================================================
// PyroSimpleSpeakerListenerLSTM — Round 12.
// Decoder GEMM -> bf16x3 split-precision MFMA (Ahi*Bhi + Ahi*Blo + Alo*Bhi),
// fragments loaded directly from global (no LDS). sig/h converted to
// bf16 hi/lo inside sample_beta / lstm_update; weights converted once
// into the dead ys buffer. Everything else = r10/r11 verified path.
// Kernels _r12.
// ====================================================================

namespace {

constexpr int MZ = 512;
constexpr int EMB = 256;
constexpr int H = 512;
constexpr int SL = 32;
constexpr int BT = 16;
constexpr int AR = 64;
constexpr int GG = 4 * H;
constexpr int RD = BT * MZ;

typedef float f32x4 __attribute__((ext_vector_type(4)));
typedef __bf16 bf16x8 __attribute__((ext_vector_type(8)));

struct KK { unsigned a, b; };

__host__ __device__ constexpr unsigned rotl32(unsigned v, int r) {
  return (v << r) | (v >> (32 - r));
}

__host__ __device__ constexpr KK tf(unsigned k0, unsigned k1, unsigned x0, unsigned x1) {
  unsigned k2 = k0 ^ k1 ^ 0x1BD11BDAu;
  x0 += k0; x1 += k1;
  x0 += x1; x1 = rotl32(x1,13); x1 ^= x0;
  x0 += x1; x1 = rotl32(x1,15); x1 ^= x0;
  x0 += x1; x1 = rotl32(x1,26); x1 ^= x0;
  x0 += x1; x1 = rotl32(x1, 6); x1 ^= x0;
  x0 += k1; x1 += k2 + 1u;
  x0 += x1; x1 = rotl32(x1,17); x1 ^= x0;
  x0 += x1; x1 = rotl32(x1,29); x1 ^= x0;
  x0 += x1; x1 = rotl32(x1,16); x1 ^= x0;
  x0 += x1; x1 = rotl32(x1,24); x1 ^= x0;
  x0 += k2; x1 += k0 + 2u;
  x0 += x1; x1 = rotl32(x1,13); x1 ^= x0;
  x0 += x1; x1 = rotl32(x1,15); x1 ^= x0;
  x0 += x1; x1 = rotl32(x1,26); x1 ^= x0;
  x0 += x1; x1 = rotl32(x1, 6); x1 ^= x0;
  x0 += k0; x1 += k1 + 3u;
  x0 += x1; x1 = rotl32(x1,17); x1 ^= x0;
  x0 += x1; x1 = rotl32(x1,29); x1 ^= x0;
  x0 += x1; x1 = rotl32(x1,16); x1 ^= x0;
  x0 += x1; x1 = rotl32(x1,24); x1 ^= x0;
  x0 += k1; x1 += k2 + 4u;
  x0 += x1; x1 = rotl32(x1,13); x1 ^= x0;
  x0 += x1; x1 = rotl32(x1,15); x1 ^= x0;
  x0 += x1; x1 = rotl32(x1,26); x1 ^= x0;
  x0 += x1; x1 = rotl32(x1, 6); x1 ^= x0;
  x0 += k2; x1 += k0 + 5u;
  return KK{x0, x1};
}

constexpr KK KEYA = tf(0u, 42u, 0u, 0u);
constexpr KK KEYB = tf(0u, 42u, 0u, 1u);

__device__ __forceinline__ void split2(KK k, KK& o0, KK& o1) {
  o0 = tf(k.a, k.b, 0u, 0u); o1 = tf(k.a, k.b, 0u, 1u);
}

__device__ __forceinline__ void split3(KK k, KK& o0, KK& o1, KK& o2) {
  o0 = tf(k.a, k.b, 0u, 0u); o1 = tf(k.a, k.b, 0u, 1u); o2 = tf(k.a, k.b, 0u, 2u);
}

__device__ __forceinline__ KK elem_key(KK gk, unsigned j) {
  return tf(gk.a, gk.b, 0u, j);
}

__device__ __forceinline__ unsigned rb32(KK k) {
  KK r = tf(k.a, k.b, 0u, 0u);
  return r.a ^ r.b;
}

__device__ __forceinline__ float u01_from_bits(unsigned bits) {
  return __uint_as_float(0x3F800000u | (bits >> 9)) - 1.0f;
}
__device__ __forceinline__ float uniform01(KK k) {
  return u01_from_bits(rb32(k));
}

__device__ float erfinv_xla(float x) {
  float xx = __fmul_rn(x, x);
  float w = -log1pf(-xx);
  float p;
  if (w < 5.0f) {
    w = __fsub_rn(w, 2.5f);
    p = 2.81022636e-08f;
    p = __fadd_rn(3.43273939e-07f, __fmul_rn(p, w));
    p = __fadd_rn(-3.5233877e-06f, __fmul_rn(p, w));
    p = __fadd_rn(-4.39150654e-06f, __fmul_rn(p, w));
    p = __fadd_rn(0.00021858087f, __fmul_rn(p, w));
    p = __fadd_rn(-0.00125372503f, __fmul_rn(p, w));
    p = __fadd_rn(-0.00417768164f, __fmul_rn(p, w));
    p = __fadd_rn(0.246640727f, __fmul_rn(p, w));
    p = __fadd_rn(1.50140941f, __fmul_rn(p, w));
  } else {
    w = __fsub_rn(__fsqrt_rn(w), 3.0f);
    p = -0.000200214257f;
    p = __fadd_rn(0.000100950558f, __fmul_rn(p, w));
    p = __fadd_rn(0.00134934322f, __fmul_rn(p, w));
    p = __fadd_rn(-0.00367342844f, __fmul_rn(p, w));
    p = __fadd_rn(0.00573950773f, __fmul_rn(p, w));
    p = __fadd_rn(-0.0076224613f, __fmul_rn(p, w));
    p = __fadd_rn(0.00943887047f, __fmul_rn(p, w));
    p = __fadd_rn(1.00167406f, __fmul_rn(p, w));
    p = __fadd_rn(2.83297682f, __fmul_rn(p, w));
  }
  return __fmul_rn(p, x);
}

__device__ __forceinline__ float normal_f(KK k) {
  float f = u01_from_bits(rb32(k));
  const float lo = __uint_as_float(0xBF7FFFFFu);
  float u = __fadd_rn(__fmul_rn(f, 2.0f), lo);
  u = fmaxf(lo, u);
  return __fmul_rn(__uint_as_float(0x3FB504F3u), erfinv_xla(u));
}

__device__ float loggamma_one(KK ekey, float alpha_orig) {
  KK key, sub;
  split2(ekey, key, sub);
  float u_boost = uniform01(sub);
  const bool boost = (alpha_orig >= 1.0f);
  const float al = boost ? alpha_orig : __fadd_rn(alpha_orig, 1.0f);
  const float third = (float)(1.0 / 3.0);
  const float d = __fsub_rn(al, third);
  const float c = __fdiv_rn(third, __fsqrt_rn(d));
  float X, V;
  for (;;) {
    KK nk, xk, uk;
    split3(key, nk, xk, uk);
    key = nk;
    float x, v;
    KK kk = xk;
    do {
      KK k2, ns;
      split2(kk, k2, ns);
      kk = k2;
      x = normal_f(ns);
      v = __fadd_rn(1.0f, __fmul_rn(x, c));
    } while (v <= 0.0f);
    X = __fmul_rn(x, x);
    V = __fmul_rn(__fmul_rn(v, v), v);
    float U = uniform01(uk);
    float sq = __fsub_rn(1.0f, __fmul_rn(0.0331f, __fmul_rn(X, X)));
    if (U < sq) break;
    float rhs = __fadd_rn(__fmul_rn(0.5f, X),
                          __fmul_rn(d, __fadd_rn(__fsub_rn(1.0f, V), logf(V))));
    if (logf(U) < rhs) break;
  }
  float ls = __fadd_rn(logf(d), logf(V));
  if (!boost)
    ls = __fadd_rn(ls, __fdiv_rn(log1pf(-u_boost), alpha_orig));
  return ls;
}

__device__ __forceinline__ float sigm(float x) { return 1.0f / (1.0f + expf(-x)); }

// fp32 -> bf16 (RNE) and hi/lo split helpers
__device__ __forceinline__ unsigned short f2bf(float x) {
  unsigned u = __float_as_uint(x);
  unsigned r = (u + 0x7fffu + ((u >> 16) & 1u)) >> 16;
  return (unsigned short)r;
}
__device__ __forceinline__ float bf2f(unsigned short h) {
  return __uint_as_float(((unsigned)h) << 16);
}
__device__ __forceinline__ void split_bf(float x, unsigned short& hi, unsigned short& lo) {
  hi = f2bf(x);
  lo = f2bf(x - bf2f(hi));
}

} // namespace

// ----------------------------- kernels ------------------------------

__global__ __launch_bounds__(256) void fill_sentinel_r12(float* o, int n) {
  int i = blockIdx.x * 256 + threadIdx.x;
  if (i < n) o[i] = 12345.0f;
}

__global__ __launch_bounds__(256) void init_states_r12(const float* __restrict__ encI,
                                                       const float* __restrict__ decI,
                                                       float* __restrict__ hE, float* __restrict__ cE,
                                                       float* __restrict__ hD, float* __restrict__ cD) {
  int idx = blockIdx.x * 256 + threadIdx.x;
  int u = idx & (H - 1);
  if (idx < MZ * H) { hE[idx] = encI[u]; cE[idx] = encI[H + u]; }
  hD[idx] = decI[u]; cD[idx] = decI[H + u];
}

// convert weights to bf16 hi/lo + bias sum (runs once, after ys is dead)
__global__ __launch_bounds__(256) void prep_dec_r12(const float* __restrict__ Wih,
                                                    const float* __restrict__ Whh,
                                                    const float* __restrict__ b1,
                                                    const float* __restrict__ b2,
                                                    unsigned short* __restrict__ WihHi,
                                                    unsigned short* __restrict__ WihLo,
                                                    unsigned short* __restrict__ WhhHi,
                                                    unsigned short* __restrict__ WhhLo,
                                                    float* __restrict__ bsum,
                                                    const float* __restrict__ hD,
                                                    unsigned short* __restrict__ hHi,
                                                    unsigned short* __restrict__ hLo) {
  int idx = blockIdx.x * 256 + threadIdx.x;   // GG*H = 1048576 threads
  split_bf(Whh[idx], WhhHi[idx], WhhLo[idx]);
  if (idx < GG * AR) split_bf(Wih[idx], WihHi[idx], WihLo[idx]);
  if (idx < GG) bsum[idx] = b1[idx] + b2[idx];
  // initial decoder h (RD*H = 4194304 = 4x this grid): strided
  for (int i = idx; i < RD * H; i += GG * H) split_bf(hD[i], hHi[i], hLo[i]);
}

// --- encoder GEMM (64x64 tile, unchanged from r10) ---
template <int MODE>
__global__ __launch_bounds__(256) void gemm_abt_r12(const float* __restrict__ A,
                                                    const float* __restrict__ B,
                                                    float* __restrict__ C,
                                                    const float* __restrict__ X1,
                                                    const float* __restrict__ X2,
                                                    int M, int N, int K) {
  __shared__ float As[16][68];
  __shared__ float Bs[16][68];
  int tid = threadIdx.x;
  int tx = tid & 15, ty = tid >> 4;
  int n0 = blockIdx.x * 64, m0 = blockIdx.y * 64;
  int lr = tid >> 2, lk4 = (tid & 3) * 4;
  float acc[4][4] = {};
  for (int k0 = 0; k0 < K; k0 += 16) {
    float4 a4 = *reinterpret_cast<const float4*>(A + (size_t)(m0 + lr) * K + k0 + lk4);
    float4 b4 = *reinterpret_cast<const float4*>(B + (size_t)(n0 + lr) * K + k0 + lk4);
    __syncthreads();
    As[lk4 + 0][lr] = a4.x; As[lk4 + 1][lr] = a4.y; As[lk4 + 2][lr] = a4.z; As[lk4 + 3][lr] = a4.w;
    Bs[lk4 + 0][lr] = b4.x; Bs[lk4 + 1][lr] = b4.y; Bs[lk4 + 2][lr] = b4.z; Bs[lk4 + 3][lr] = b4.w;
    __syncthreads();
#pragma unroll
    for (int k = 0; k < 16; ++k) {
      float av[4], bv[4];
#pragma unroll
      for (int i = 0; i < 4; ++i) av[i] = As[k][ty * 4 + i];
#pragma unroll
      for (int j = 0; j < 4; ++j) bv[j] = Bs[k][tx * 4 + j];
#pragma unroll
      for (int i = 0; i < 4; ++i)
#pragma unroll
        for (int j = 0; j < 4; ++j) acc[i][j] = fmaf(av[i], bv[j], acc[i][j]);
    }
  }
#pragma unroll
  for (int i = 0; i < 4; ++i) {
    int m = m0 + ty * 4 + i;
#pragma unroll
    for (int j = 0; j < 4; ++j) {
      int n = n0 + tx * 4 + j;
      float v = acc[i][j];
      if (MODE == 1) v += X1[n] + X2[n];
      if (MODE == 2) v += X1[(size_t)m * N + n];
      C[(size_t)m * N + n] = v;
    }
  }
}

// --- decoder fused-gates GEMM via bf16x3 MFMA, fragments from global ---
// gates[RD][GG] = sig[RD,64]@Wih^T + h[RD,512]@Whh^T + bsum[n]
// block 256 thr = 4 waves (2x2), tile 128x128; wave 64x64 = 4x4 MFMA frags
__global__ __launch_bounds__(256) void mfma_dec_r12(
    const unsigned short* __restrict__ sigHi, const unsigned short* __restrict__ sigLo,
    const unsigned short* __restrict__ hHi,  const unsigned short* __restrict__ hLo,
    const unsigned short* __restrict__ WihHi, const unsigned short* __restrict__ WihLo,
    const unsigned short* __restrict__ WhhHi, const unsigned short* __restrict__ WhhLo,
    const float* __restrict__ bsum,
    float* __restrict__ gates) {
  int tid = threadIdx.x;
  int lane = tid & 63, wid = tid >> 6;
  int wr = wid >> 1, wc = wid & 1;
  int m0 = blockIdx.y * 128 + wr * 64;
  int n0 = blockIdx.x * 128 + wc * 64;
  int lr = lane & 15;           // row within 16x16 frag
  int lk = (lane >> 4) * 8;     // k offset within frag
  f32x4 acc[4][4] = {};
#pragma unroll
  for (int phase = 0; phase < 2; ++phase) {
    const unsigned short* Ah = phase ? hHi : sigHi;
    const unsigned short* Al = phase ? hLo : sigLo;
    const unsigned short* Bh = phase ? WhhHi : WihHi;
    const unsigned short* Bl = phase ? WhhLo : WihLo;
    const int K = phase ? H : AR;
    for (int k0 = 0; k0 < K; k0 += 32) {
      bf16x8 ah[4], al[4], bh[4], bl[4];
#pragma unroll
      for (int f = 0; f < 4; ++f) {
        size_t ao = (size_t)(m0 + f * 16 + lr) * K + k0 + lk;
        ah[f] = *reinterpret_cast<const bf16x8*>(Ah + ao);
        al[f] = *reinterpret_cast<const bf16x8*>(Al + ao);
        size_t bo = (size_t)(n0 + f * 16 + lr) * K + k0 + lk;
        bh[f] = *reinterpret_cast<const bf16x8*>(Bh + bo);
        bl[f] = *reinterpret_cast<const bf16x8*>(Bl + bo);
      }
#pragma unroll
      for (int i = 0; i < 4; ++i)
#pragma unroll
        for (int j = 0; j < 4; ++j) {
          acc[i][j] = __builtin_amdgcn_mfma_f32_16x16x32_bf16(ah[i], bh[j], acc[i][j], 0, 0, 0);
          acc[i][j] = __builtin_amdgcn_mfma_f32_16x16x32_bf16(ah[i], bl[j], acc[i][j], 0, 0, 0);
          acc[i][j] = __builtin_amdgcn_mfma_f32_16x16x32_bf16(al[i], bh[j], acc[i][j], 0, 0, 0);
        }
    }
  }
  // C/D layout: col = lane&15, row = (lane>>4)*4 + reg   [m89-verified]
  int crow = (lane >> 4) * 4;
  int ccol = lane & 15;
#pragma unroll
  for (int j = 0; j < 4; ++j) {
    int n = n0 + j * 16 + ccol;
    float b = bsum[n];
#pragma unroll
    for (int i = 0; i < 4; ++i) {
#pragma unroll
      for (int r = 0; r < 4; ++r) {
        int m = m0 + i * 16 + crow + r;
        gates[(size_t)m * GG + n] = acc[i][j][r] + b;
      }
    }
  }
}

// C[M,N] = A[M,K] @ B[K,N]. EPI 0: plain. EPI 1: softplus + even/odd split (N=128).
template <int EPI>
__global__ __launch_bounds__(256) void gemm_ab_r12(const float* __restrict__ A,
                                                   const float* __restrict__ B,
                                                   float* __restrict__ C0,
                                                   float* __restrict__ C1,
                                                   int M, int N, int K) {
  __shared__ float As[16][68];
  __shared__ float Bs[16][68];
  int tid = threadIdx.x;
  int tx = tid & 15, ty = tid >> 4;
  int n0 = blockIdx.x * 64, m0 = blockIdx.y * 64;
  int lr = tid >> 2, lk4 = (tid & 3) * 4;
  int bk = tid >> 4, bn4 = (tid & 15) * 4;
  float acc[4][4] = {};
  for (int k0 = 0; k0 < K; k0 += 16) {
    float4 a4 = *reinterpret_cast<const float4*>(A + (size_t)(m0 + lr) * K + k0 + lk4);
    float4 b4 = *reinterpret_cast<const float4*>(B + (size_t)(k0 + bk) * N + n0 + bn4);
    __syncthreads();
    As[lk4 + 0][lr] = a4.x; As[lk4 + 1][lr] = a4.y; As[lk4 + 2][lr] = a4.z; As[lk4 + 3][lr] = a4.w;
    *reinterpret_cast<float4*>(&Bs[bk][bn4]) = b4;
    __syncthreads();
#pragma unroll
    for (int k = 0; k < 16; ++k) {
      float av[4], bv[4];
#pragma unroll
      for (int i = 0; i < 4; ++i) av[i] = As[k][ty * 4 + i];
#pragma unroll
      for (int j = 0; j < 4; ++j) bv[j] = Bs[k][tx * 4 + j];
#pragma unroll
      for (int i = 0; i < 4; ++i)
#pragma unroll
        for (int j = 0; j < 4; ++j) acc[i][j] = fmaf(av[i], bv[j], acc[i][j]);
    }
  }
#pragma unroll
  for (int i = 0; i < 4; ++i) {
    size_t m = (size_t)(m0 + ty * 4 + i);
#pragma unroll
    for (int j = 0; j < 4; ++j) {
      int n = n0 + tx * 4 + j;
      float v = acc[i][j];
      if (EPI == 0) {
        C0[m * N + n] = v;
      } else {
        float sp = fmaxf(v, 0.0f) + log1pf(expf(-fabsf(v)));
        if (n & 1) C1[m * (N / 2) + (n >> 1)] = sp;
        else       C0[m * (N / 2) + (n >> 1)] = sp;
      }
    }
  }
}

// encoder lstm update (writes ys fp32)
__global__ __launch_bounds__(256) void lstm_update_r12(float* __restrict__ h, float* __restrict__ c,
                                                       const float* __restrict__ gates,
                                                       float* __restrict__ ysOut) {
  int idx = blockIdx.x * 256 + threadIdx.x;
  int r = idx >> 9, u = idx & (H - 1);
  const float* g = gates + (size_t)r * GG;
  float gi = g[u], gf = g[u + H], gg = g[u + 2 * H], go = g[u + 3 * H];
  float cn = sigm(gf) * c[idx] + sigm(gi) * tanhf(gg);
  float hn = sigm(go) * tanhf(cn);
  c[idx] = cn; h[idx] = hn;
  if (ysOut) ysOut[idx] = hn;
}

// decoder lstm update: also writes h as bf16 hi/lo for the MFMA GEMM
__global__ __launch_bounds__(256) void lstm_dec_r12(float* __restrict__ h, float* __restrict__ c,
                                                    const float* __restrict__ gates,
                                                    unsigned short* __restrict__ hHi,
                                                    unsigned short* __restrict__ hLo) {
  int idx = blockIdx.x * 256 + threadIdx.x;
  int r = idx >> 9, u = idx & (H - 1);
  const float* g = gates + (size_t)r * GG;
  float gi = g[u], gf = g[u + H], gg = g[u + 2 * H], go = g[u + 3 * H];
  float cn = sigm(gf) * c[idx] + sigm(gi) * tanhf(gg);
  float hn = sigm(go) * tanhf(cn);
  c[idx] = cn; h[idx] = hn;
  split_bf(hn, hHi[idx], hLo[idx]);
}

__global__ __launch_bounds__(256) void sample_beta_r12(const float* __restrict__ alphaA,
                                                       const float* __restrict__ betaA,
                                                       unsigned short* __restrict__ sigHi,
                                                       unsigned short* __restrict__ sigLo,
                                                       int s) {
  unsigned idx = blockIdx.x * 256 + threadIdx.x;
  unsigned r = idx >> 6;
  unsigned j = idx & 63u;
  unsigned b = r >> 9;
  unsigned m = r & 511u;
  size_t ab = ((size_t)s * MZ + m) * AR + j;
  float alpha = alphaA[ab];
  float beta = betaA[ab];
  unsigned jl = ((b * 32u + (unsigned)s) * 512u + m) * 64u + j;
  float lga = loggamma_one(elem_key(KEYA, jl), alpha);
  float lgb = loggamma_one(elem_key(KEYB, jl), beta);
  float lm = fmaxf(lga, lgb);
  float ea = expf(__fsub_rn(lga, lm));
  float eb = expf(__fsub_rn(lgb, lm));
  float sv = __fdiv_rn(ea, __fadd_rn(ea, eb));
  split_bf(sv, sigHi[idx], sigLo[idx]);
}

__global__ __launch_bounds__(256) void softmax_rows_r12(const float* __restrict__ L,
                                                        float* __restrict__ O) {
  __shared__ float red[8];
  int r = blockIdx.x;
  const float* row = L + (size_t)r * H;
  int t = threadIdx.x;
  float a = row[t], b = row[t + 256];
  float m = fmaxf(a, b);
#pragma unroll
  for (int o = 1; o < 64; o <<= 1) m = fmaxf(m, __shfl_xor(m, o));
  if ((t & 63) == 0) red[t >> 6] = m;
  __syncthreads();
  m = fmaxf(fmaxf(red[0], red[1]), fmaxf(red[2], red[3]));
  float e0 = expf(a - m), e1 = expf(b - m);
  float s = e0 + e1;
#pragma unroll
  for (int o = 1; o < 64; o <<= 1) s += __shfl_xor(s, o);
  if ((t & 63) == 0) red[4 + (t >> 6)] = s;
  __syncthreads();
  s = red[4] + red[5] + red[6] + red[7];
  O[(size_t)r * H + t] = e0 / s;
  O[(size_t)r * H + t + 256] = e1 / s;
}

// ----------------------------- launcher -----------------------------

extern "C" void kernel_launch(void* const* d_in, const int* in_sizes, int n_in,
                              void* d_out, int out_size, void* d_ws, size_t ws_size,
                              hipStream_t stream) {
  (void)in_sizes; (void)n_in;
  const float* embedding = (const float*)d_in[2];
  const float* eWih = (const float*)d_in[3];
  const float* eWhh = (const float*)d_in[4];
  const float* ebih = (const float*)d_in[5];
  const float* ebhh = (const float*)d_in[6];
  const float* eInit = (const float*)d_in[7];
  const float* dWih = (const float*)d_in[8];
  const float* dWhh = (const float*)d_in[9];
  const float* dbih = (const float*)d_in[10];
  const float* dbhh = (const float*)d_in[11];
  const float* dInit = (const float*)d_in[12];
  const float* Wp = (const float*)d_in[13];
  const float* Wo = (const float*)d_in[14];
  float* out = (float*)d_out;
  float* w = (float*)d_ws;

  size_t o = 0;
  float* xW     = w + o; o += (size_t)MZ * GG;
  float* hE     = w + o; o += (size_t)MZ * H;
  float* cE     = w + o; o += (size_t)MZ * H;
  float* ys     = w + o; o += (size_t)SL * MZ * H;     // 8388608 floats; reused below
  float* alphaA = w + o; o += (size_t)SL * MZ * AR;
  float* betaA  = w + o; o += (size_t)SL * MZ * AR;
  float* hD     = w + o; o += (size_t)RD * H;
  float* cD     = w + o; o += (size_t)RD * H;
  float* gates  = w + o; o += (size_t)RD * GG;         // reused as logits
  if (ws_size < o * sizeof(float)) {
    fill_sentinel_r12<<<(out_size + 255) / 256, 256, 0, stream>>>(out, out_size);
    return;
  }
  float* logits = gates;

  // bf16 hi/lo buffers OVERLAID on ys (dead after params GEMM):
  // need sigHi/Lo (RD*AR each) + hHi/Lo (RD*H each) + Wih/Whh hi/lo + bsum
  // = 2*(512K) + 2*(4.19M) + 2*(128K) + 2*(1.05M) shorts + 2K floats
  // = 11.7M shorts + 2K floats < 8.39M floats. Fits.
  {
    size_t so = 0;
    unsigned short* sbase = (unsigned short*)ys;
    (void)sbase; (void)so;
  }
  unsigned short* sigHi = (unsigned short*)ys;                    // RD*AR
  unsigned short* sigLo = sigHi + (size_t)RD * AR;
  unsigned short* hHi   = sigLo + (size_t)RD * AR;                // RD*H
  unsigned short* hLo   = hHi + (size_t)RD * H;
  unsigned short* WihHi = hLo + (size_t)RD * H;                   // GG*AR
  unsigned short* WihLo = WihHi + (size_t)GG * AR;
  unsigned short* WhhHi = WihLo + (size_t)GG * AR;                // GG*H
  unsigned short* WhhLo = WhhHi + (size_t)GG * H;
  float* bsum = (float*)(WhhLo + (size_t)GG * H);                 // GG floats

  init_states_r12<<<(RD * H) / 256, 256, 0, stream>>>(eInit, dInit, hE, cE, hD, cD);

  gemm_abt_r12<1><<<dim3(GG / 64, MZ / 64), 256, 0, stream>>>(embedding, eWih, xW, ebih, ebhh, MZ, GG, EMB);

  for (int s = 0; s < SL; ++s) {
    gemm_abt_r12<2><<<dim3(GG / 64, MZ / 64), 256, 0, stream>>>(hE, eWhh, gates, xW, nullptr, MZ, GG, H);
    lstm_update_r12<<<(MZ * H) / 256, 256, 0, stream>>>(hE, cE, gates, ys + (size_t)s * MZ * H);
  }

  gemm_ab_r12<1><<<dim3(128 / 64, (SL * MZ) / 64), 256, 0, stream>>>(ys, Wp, alphaA, betaA, SL * MZ, 128, H);

  // ys is now dead -> build bf16 hi/lo weights + initial h split in overlay
  prep_dec_r12<<<(GG * H) / 256, 256, 0, stream>>>(dWih, dWhh, dbih, dbhh,
                                                   WihHi, WihLo, WhhHi, WhhLo, bsum,
                                                   hD, hHi, hLo);

  for (int s = 0; s < SL; ++s) {
    sample_beta_r12<<<(RD * AR) / 256, 256, 0, stream>>>(alphaA, betaA, sigHi, sigLo, s);
    mfma_dec_r12<<<dim3(GG / 128, RD / 128), 256, 0, stream>>>(sigHi, sigLo, hHi, hLo,
                                                               WihHi, WihLo, WhhHi, WhhLo,
                                                               bsum, gates);
    lstm_dec_r12<<<(RD * H) / 256, 256, 0, stream>>>(hD, cD, gates, hHi, hLo);
  }

  gemm_ab_r12<0><<<dim3(H / 64, RD / 64), 256, 0, stream>>>(hD, Wo, logits, nullptr, RD, H, H);
  softmax_rows_r12<<<RD, 256, 0, stream>>>(logits, out);
}

// Round 13
// 7016.558 us; speedup vs baseline: 1.5303x; 1.0551x over previous
//
#include <hip/hip_runtime.h>
#include <cstdint>
#include <cstddef>

// ====================================================================
// PyroSimpleSpeakerListenerLSTM — Round 13.
// Fuse decoder LSTM into the MFMA epilogue (wave tile = 64 rows x 16 u
// x 4 gates) -> gates buffer eliminated (67MB/step HBM round-trip) and
// lstm_dec kernels removed. h bf16 hi/lo ping-pongs between two buffer
// pairs. Gate accumulation is fragment-for-fragment identical to r12
// => bitwise-identical output. Kernels _r13.
// ====================================================================

namespace {

constexpr int MZ = 512;
constexpr int EMB = 256;
constexpr int H = 512;
constexpr int SL = 32;
constexpr int BT = 16;
constexpr int AR = 64;
constexpr int GG = 4 * H;
constexpr int RD = BT * MZ;

typedef float f32x4 __attribute__((ext_vector_type(4)));
typedef __bf16 bf16x8 __attribute__((ext_vector_type(8)));

struct KK { unsigned a, b; };

__host__ __device__ constexpr unsigned rotl32(unsigned v, int r) {
  return (v << r) | (v >> (32 - r));
}

__host__ __device__ constexpr KK tf(unsigned k0, unsigned k1, unsigned x0, unsigned x1) {
  unsigned k2 = k0 ^ k1 ^ 0x1BD11BDAu;
  x0 += k0; x1 += k1;
  x0 += x1; x1 = rotl32(x1,13); x1 ^= x0;
  x0 += x1; x1 = rotl32(x1,15); x1 ^= x0;
  x0 += x1; x1 = rotl32(x1,26); x1 ^= x0;
  x0 += x1; x1 = rotl32(x1, 6); x1 ^= x0;
  x0 += k1; x1 += k2 + 1u;
  x0 += x1; x1 = rotl32(x1,17); x1 ^= x0;
  x0 += x1; x1 = rotl32(x1,29); x1 ^= x0;
  x0 += x1; x1 = rotl32(x1,16); x1 ^= x0;
  x0 += x1; x1 = rotl32(x1,24); x1 ^= x0;
  x0 += k2; x1 += k0 + 2u;
  x0 += x1; x1 = rotl32(x1,13); x1 ^= x0;
  x0 += x1; x1 = rotl32(x1,15); x1 ^= x0;
  x0 += x1; x1 = rotl32(x1,26); x1 ^= x0;
  x0 += x1; x1 = rotl32(x1, 6); x1 ^= x0;
  x0 += k0; x1 += k1 + 3u;
  x0 += x1; x1 = rotl32(x1,17); x1 ^= x0;
  x0 += x1; x1 = rotl32(x1,29); x1 ^= x0;
  x0 += x1; x1 = rotl32(x1,16); x1 ^= x0;
  x0 += x1; x1 = rotl32(x1,24); x1 ^= x0;
  x0 += k1; x1 += k2 + 4u;
  x0 += x1; x1 = rotl32(x1,13); x1 ^= x0;
  x0 += x1; x1 = rotl32(x1,15); x1 ^= x0;
  x0 += x1; x1 = rotl32(x1,26); x1 ^= x0;
  x0 += x1; x1 = rotl32(x1, 6); x1 ^= x0;
  x0 += k2; x1 += k0 + 5u;
  return KK{x0, x1};
}

constexpr KK KEYA = tf(0u, 42u, 0u, 0u);
constexpr KK KEYB = tf(0u, 42u, 0u, 1u);

__device__ __forceinline__ void split2(KK k, KK& o0, KK& o1) {
  o0 = tf(k.a, k.b, 0u, 0u); o1 = tf(k.a, k.b, 0u, 1u);
}

__device__ __forceinline__ void split3(KK k, KK& o0, KK& o1, KK& o2) {
  o0 = tf(k.a, k.b, 0u, 0u); o1 = tf(k.a, k.b, 0u, 1u); o2 = tf(k.a, k.b, 0u, 2u);
}

__device__ __forceinline__ KK elem_key(KK gk, unsigned j) {
  return tf(gk.a, gk.b, 0u, j);
}

__device__ __forceinline__ unsigned rb32(KK k) {
  KK r = tf(k.a, k.b, 0u, 0u);
  return r.a ^ r.b;
}

__device__ __forceinline__ float u01_from_bits(unsigned bits) {
  return __uint_as_float(0x3F800000u | (bits >> 9)) - 1.0f;
}
__device__ __forceinline__ float uniform01(KK k) {
  return u01_from_bits(rb32(k));
}

__device__ float erfinv_xla(float x) {
  float xx = __fmul_rn(x, x);
  float w = -log1pf(-xx);
  float p;
  if (w < 5.0f) {
    w = __fsub_rn(w, 2.5f);
    p = 2.81022636e-08f;
    p = __fadd_rn(3.43273939e-07f, __fmul_rn(p, w));
    p = __fadd_rn(-3.5233877e-06f, __fmul_rn(p, w));
    p = __fadd_rn(-4.39150654e-06f, __fmul_rn(p, w));
    p = __fadd_rn(0.00021858087f, __fmul_rn(p, w));
    p = __fadd_rn(-0.00125372503f, __fmul_rn(p, w));
    p = __fadd_rn(-0.00417768164f, __fmul_rn(p, w));
    p = __fadd_rn(0.246640727f, __fmul_rn(p, w));
    p = __fadd_rn(1.50140941f, __fmul_rn(p, w));
  } else {
    w = __fsub_rn(__fsqrt_rn(w), 3.0f);
    p = -0.000200214257f;
    p = __fadd_rn(0.000100950558f, __fmul_rn(p, w));
    p = __fadd_rn(0.00134934322f, __fmul_rn(p, w));
    p = __fadd_rn(-0.00367342844f, __fmul_rn(p, w));
    p = __fadd_rn(0.00573950773f, __fmul_rn(p, w));
    p = __fadd_rn(-0.0076224613f, __fmul_rn(p, w));
    p = __fadd_rn(0.00943887047f, __fmul_rn(p, w));
    p = __fadd_rn(1.00167406f, __fmul_rn(p, w));
    p = __fadd_rn(2.83297682f, __fmul_rn(p, w));
  }
  return __fmul_rn(p, x);
}

__device__ __forceinline__ float normal_f(KK k) {
  float f = u01_from_bits(rb32(k));
  const float lo = __uint_as_float(0xBF7FFFFFu);
  float u = __fadd_rn(__fmul_rn(f, 2.0f), lo);
  u = fmaxf(lo, u);
  return __fmul_rn(__uint_as_float(0x3FB504F3u), erfinv_xla(u));
}

__device__ float loggamma_one(KK ekey, float alpha_orig) {
  KK key, sub;
  split2(ekey, key, sub);
  float u_boost = uniform01(sub);
  const bool boost = (alpha_orig >= 1.0f);
  const float al = boost ? alpha_orig : __fadd_rn(alpha_orig, 1.0f);
  const float third = (float)(1.0 / 3.0);
  const float d = __fsub_rn(al, third);
  const float c = __fdiv_rn(third, __fsqrt_rn(d));
  float X, V;
  for (;;) {
    KK nk, xk, uk;
    split3(key, nk, xk, uk);
    key = nk;
    float x, v;
    KK kk = xk;
    do {
      KK k2, ns;
      split2(kk, k2, ns);
      kk = k2;
      x = normal_f(ns);
      v = __fadd_rn(1.0f, __fmul_rn(x, c));
    } while (v <= 0.0f);
    X = __fmul_rn(x, x);
    V = __fmul_rn(__fmul_rn(v, v), v);
    float U = uniform01(uk);
    float sq = __fsub_rn(1.0f, __fmul_rn(0.0331f, __fmul_rn(X, X)));
    if (U < sq) break;
    float rhs = __fadd_rn(__fmul_rn(0.5f, X),
                          __fmul_rn(d, __fadd_rn(__fsub_rn(1.0f, V), logf(V))));
    if (logf(U) < rhs) break;
  }
  float ls = __fadd_rn(logf(d), logf(V));
  if (!boost)
    ls = __fadd_rn(ls, __fdiv_rn(log1pf(-u_boost), alpha_orig));
  return ls;
}

__device__ __forceinline__ float sigm(float x) { return 1.0f / (1.0f + expf(-x)); }

__device__ __forceinline__ unsigned short f2bf(float x) {
  unsigned u = __float_as_uint(x);
  unsigned r = (u + 0x7fffu + ((u >> 16) & 1u)) >> 16;
  return (unsigned short)r;
}
__device__ __forceinline__ float bf2f(unsigned short h) {
  return __uint_as_float(((unsigned)h) << 16);
}
__device__ __forceinline__ void split_bf(float x, unsigned short& hi, unsigned short& lo) {
  hi = f2bf(x);
  lo = f2bf(x - bf2f(hi));
}

} // namespace

// ----------------------------- kernels ------------------------------

__global__ __launch_bounds__(256) void fill_sentinel_r13(float* o, int n) {
  int i = blockIdx.x * 256 + threadIdx.x;
  if (i < n) o[i] = 12345.0f;
}

__global__ __launch_bounds__(256) void init_states_r13(const float* __restrict__ encI,
                                                       const float* __restrict__ decI,
                                                       float* __restrict__ hE, float* __restrict__ cE,
                                                       float* __restrict__ hD, float* __restrict__ cD) {
  int idx = blockIdx.x * 256 + threadIdx.x;
  int u = idx & (H - 1);
  if (idx < MZ * H) { hE[idx] = encI[u]; cE[idx] = encI[H + u]; }
  hD[idx] = decI[u]; cD[idx] = decI[H + u];
}

// convert weights to bf16 hi/lo + bias sum + split initial h
__global__ __launch_bounds__(256) void prep_dec_r13(const float* __restrict__ Wih,
                                                    const float* __restrict__ Whh,
                                                    const float* __restrict__ b1,
                                                    const float* __restrict__ b2,
                                                    unsigned short* __restrict__ WihHi,
                                                    unsigned short* __restrict__ WihLo,
                                                    unsigned short* __restrict__ WhhHi,
                                                    unsigned short* __restrict__ WhhLo,
                                                    float* __restrict__ bsum,
                                                    const float* __restrict__ hD,
                                                    unsigned short* __restrict__ hHi,
                                                    unsigned short* __restrict__ hLo) {
  int idx = blockIdx.x * 256 + threadIdx.x;   // GG*H threads
  split_bf(Whh[idx], WhhHi[idx], WhhLo[idx]);
  if (idx < GG * AR) split_bf(Wih[idx], WihHi[idx], WihLo[idx]);
  if (idx < GG) bsum[idx] = b1[idx] + b2[idx];
  for (int i = idx; i < RD * H; i += GG * H) split_bf(hD[i], hHi[i], hLo[i]);
}

// --- encoder GEMM (64x64 tile, unchanged) ---
template <int MODE>
__global__ __launch_bounds__(256) void gemm_abt_r13(const float* __restrict__ A,
                                                    const float* __restrict__ B,
                                                    float* __restrict__ C,
                                                    const float* __restrict__ X1,
                                                    const float* __restrict__ X2,
                                                    int M, int N, int K) {
  __shared__ float As[16][68];
  __shared__ float Bs[16][68];
  int tid = threadIdx.x;
  int tx = tid & 15, ty = tid >> 4;
  int n0 = blockIdx.x * 64, m0 = blockIdx.y * 64;
  int lr = tid >> 2, lk4 = (tid & 3) * 4;
  float acc[4][4] = {};
  for (int k0 = 0; k0 < K; k0 += 16) {
    float4 a4 = *reinterpret_cast<const float4*>(A + (size_t)(m0 + lr) * K + k0 + lk4);
    float4 b4 = *reinterpret_cast<const float4*>(B + (size_t)(n0 + lr) * K + k0 + lk4);
    __syncthreads();
    As[lk4 + 0][lr] = a4.x; As[lk4 + 1][lr] = a4.y; As[lk4 + 2][lr] = a4.z; As[lk4 + 3][lr] = a4.w;
    Bs[lk4 + 0][lr] = b4.x; Bs[lk4 + 1][lr] = b4.y; Bs[lk4 + 2][lr] = b4.z; Bs[lk4 + 3][lr] = b4.w;
    __syncthreads();
#pragma unroll
    for (int k = 0; k < 16; ++k) {
      float av[4], bv[4];
#pragma unroll
      for (int i = 0; i < 4; ++i) av[i] = As[k][ty * 4 + i];
#pragma unroll
      for (int j = 0; j < 4; ++j) bv[j] = Bs[k][tx * 4 + j];
#pragma unroll
      for (int i = 0; i < 4; ++i)
#pragma unroll
        for (int j = 0; j < 4; ++j) acc[i][j] = fmaf(av[i], bv[j], acc[i][j]);
    }
  }
#pragma unroll
  for (int i = 0; i < 4; ++i) {
    int m = m0 + ty * 4 + i;
#pragma unroll
    for (int j = 0; j < 4; ++j) {
      int n = n0 + tx * 4 + j;
      float v = acc[i][j];
      if (MODE == 1) v += X1[n] + X2[n];
      if (MODE == 2) v += X1[(size_t)m * N + n];
      C[(size_t)m * N + n] = v;
    }
  }
}

// --- fused decoder step: bf16x3 MFMA gates + in-register LSTM update ---
// wave tile: 64 rows x 16 u x 4 gates. B rows = g*512 + u0 + lr.
__global__ __launch_bounds__(256) void mfma_lstm_r13(
    const unsigned short* __restrict__ sigHi, const unsigned short* __restrict__ sigLo,
    const unsigned short* __restrict__ hHiIn, const unsigned short* __restrict__ hLoIn,
    const unsigned short* __restrict__ WihHi, const unsigned short* __restrict__ WihLo,
    const unsigned short* __restrict__ WhhHi, const unsigned short* __restrict__ WhhLo,
    const float* __restrict__ bsum,
    float* __restrict__ hD, float* __restrict__ cD,
    unsigned short* __restrict__ hHiOut, unsigned short* __restrict__ hLoOut,
    int writeHF) {
  int tid = threadIdx.x;
  int lane = tid & 63, wid = tid >> 6;
  int wr = wid >> 1, wu = wid & 1;
  int m0 = blockIdx.y * 128 + wr * 64;
  int u0 = blockIdx.x * 32 + wu * 16;
  int lr = lane & 15;
  int lk = (lane >> 4) * 8;
  f32x4 acc[4][4] = {};   // [row frag i][gate g]
#pragma unroll
  for (int phase = 0; phase < 2; ++phase) {
    const unsigned short* Ah = phase ? hHiIn : sigHi;
    const unsigned short* Al = phase ? hLoIn : sigLo;
    const unsigned short* Bh = phase ? WhhHi : WihHi;
    const unsigned short* Bl = phase ? WhhLo : WihLo;
    const int K = phase ? H : AR;
    for (int k0 = 0; k0 < K; k0 += 32) {
      bf16x8 ah[4], al[4], bh[4], bl[4];
#pragma unroll
      for (int f = 0; f < 4; ++f) {
        size_t ao = (size_t)(m0 + f * 16 + lr) * K + k0 + lk;
        ah[f] = *reinterpret_cast<const bf16x8*>(Ah + ao);
        al[f] = *reinterpret_cast<const bf16x8*>(Al + ao);
        size_t bo = (size_t)(f * 512 + u0 + lr) * K + k0 + lk;   // f == gate here
        bh[f] = *reinterpret_cast<const bf16x8*>(Bh + bo);
        bl[f] = *reinterpret_cast<const bf16x8*>(Bl + bo);
      }
#pragma unroll
      for (int i = 0; i < 4; ++i)
#pragma unroll
        for (int g = 0; g < 4; ++g) {
          acc[i][g] = __builtin_amdgcn_mfma_f32_16x16x32_bf16(ah[i], bh[g], acc[i][g], 0, 0, 0);
          acc[i][g] = __builtin_amdgcn_mfma_f32_16x16x32_bf16(ah[i], bl[g], acc[i][g], 0, 0, 0);
          acc[i][g] = __builtin_amdgcn_mfma_f32_16x16x32_bf16(al[i], bh[g], acc[i][g], 0, 0, 0);
        }
    }
  }
  // C/D layout: col = lane&15, row = (lane>>4)*4 + reg   [m89-verified]
  int crow = (lane >> 4) * 4;
  int u = u0 + (lane & 15);
  float bi = bsum[u], bff = bsum[u + 512], bg = bsum[u + 1024], bo = bsum[u + 1536];
#pragma unroll
  for (int i = 0; i < 4; ++i) {
#pragma unroll
    for (int r = 0; r < 4; ++r) {
      int m = m0 + i * 16 + crow + r;
      size_t idx = (size_t)m * H + u;
      float gi = acc[i][0][r] + bi;
      float gf = acc[i][1][r] + bff;
      float gg = acc[i][2][r] + bg;
      float go = acc[i][3][r] + bo;
      float cn = sigm(gf) * cD[idx] + sigm(gi) * tanhf(gg);
      float hn = sigm(go) * tanhf(cn);
      cD[idx] = cn;
      if (writeHF) hD[idx] = hn;
      split_bf(hn, hHiOut[idx], hLoOut[idx]);
    }
  }
}

// C[M,N] = A[M,K] @ B[K,N]. EPI 0: plain. EPI 1: softplus + even/odd split (N=128).
template <int EPI>
__global__ __launch_bounds__(256) void gemm_ab_r13(const float* __restrict__ A,
                                                   const float* __restrict__ B,
                                                   float* __restrict__ C0,
                                                   float* __restrict__ C1,
                                                   int M, int N, int K) {
  __shared__ float As[16][68];
  __shared__ float Bs[16][68];
  int tid = threadIdx.x;
  int tx = tid & 15, ty = tid >> 4;
  int n0 = blockIdx.x * 64, m0 = blockIdx.y * 64;
  int lr = tid >> 2, lk4 = (tid & 3) * 4;
  int bk = tid >> 4, bn4 = (tid & 15) * 4;
  float acc[4][4] = {};
  for (int k0 = 0; k0 < K; k0 += 16) {
    float4 a4 = *reinterpret_cast<const float4*>(A + (size_t)(m0 + lr) * K + k0 + lk4);
    float4 b4 = *reinterpret_cast<const float4*>(B + (size_t)(k0 + bk) * N + n0 + bn4);
    __syncthreads();
    As[lk4 + 0][lr] = a4.x; As[lk4 + 1][lr] = a4.y; As[lk4 + 2][lr] = a4.z; As[lk4 + 3][lr] = a4.w;
    *reinterpret_cast<float4*>(&Bs[bk][bn4]) = b4;
    __syncthreads();
#pragma unroll
    for (int k = 0; k < 16; ++k) {
      float av[4], bv[4];
#pragma unroll
      for (int i = 0; i < 4; ++i) av[i] = As[k][ty * 4 + i];
#pragma unroll
      for (int j = 0; j < 4; ++j) bv[j] = Bs[k][tx * 4 + j];
#pragma unroll
      for (int i = 0; i < 4; ++i)
#pragma unroll
        for (int j = 0; j < 4; ++j) acc[i][j] = fmaf(av[i], bv[j], acc[i][j]);
    }
  }
#pragma unroll
  for (int i = 0; i < 4; ++i) {
    size_t m = (size_t)(m0 + ty * 4 + i);
#pragma unroll
    for (int j = 0; j < 4; ++j) {
      int n = n0 + tx * 4 + j;
      float v = acc[i][j];
      if (EPI == 0) {
        C0[m * N + n] = v;
      } else {
        float sp = fmaxf(v, 0.0f) + log1pf(expf(-fabsf(v)));
        if (n & 1) C1[m * (N / 2) + (n >> 1)] = sp;
        else       C0[m * (N / 2) + (n >> 1)] = sp;
      }
    }
  }
}

// encoder lstm update (writes ys fp32)
__global__ __launch_bounds__(256) void lstm_update_r13(float* __restrict__ h, float* __restrict__ c,
                                                       const float* __restrict__ gates,
                                                       float* __restrict__ ysOut) {
  int idx = blockIdx.x * 256 + threadIdx.x;
  int r = idx >> 9, u = idx & (H - 1);
  const float* g = gates + (size_t)r * GG;
  float gi = g[u], gf = g[u + H], gg = g[u + 2 * H], go = g[u + 3 * H];
  float cn = sigm(gf) * c[idx] + sigm(gi) * tanhf(gg);
  float hn = sigm(go) * tanhf(cn);
  c[idx] = cn; h[idx] = hn;
  if (ysOut) ysOut[idx] = hn;
}

__global__ __launch_bounds__(256) void sample_beta_r13(const float* __restrict__ alphaA,
                                                       const float* __restrict__ betaA,
                                                       unsigned short* __restrict__ sigHi,
                                                       unsigned short* __restrict__ sigLo,
                                                       int s) {
  unsigned idx = blockIdx.x * 256 + threadIdx.x;
  unsigned r = idx >> 6;
  unsigned j = idx & 63u;
  unsigned b = r >> 9;
  unsigned m = r & 511u;
  size_t ab = ((size_t)s * MZ + m) * AR + j;
  float alpha = alphaA[ab];
  float beta = betaA[ab];
  unsigned jl = ((b * 32u + (unsigned)s) * 512u + m) * 64u + j;
  float lga = loggamma_one(elem_key(KEYA, jl), alpha);
  float lgb = loggamma_one(elem_key(KEYB, jl), beta);
  float lm = fmaxf(lga, lgb);
  float ea = expf(__fsub_rn(lga, lm));
  float eb = expf(__fsub_rn(lgb, lm));
  float sv = __fdiv_rn(ea, __fadd_rn(ea, eb));
  split_bf(sv, sigHi[idx], sigLo[idx]);
}

__global__ __launch_bounds__(256) void softmax_rows_r13(const float* __restrict__ L,
                                                        float* __restrict__ O) {
  __shared__ float red[8];
  int r = blockIdx.x;
  const float* row = L + (size_t)r * H;
  int t = threadIdx.x;
  float a = row[t], b = row[t + 256];
  float m = fmaxf(a, b);
#pragma unroll
  for (int o = 1; o < 64; o <<= 1) m = fmaxf(m, __shfl_xor(m, o));
  if ((t & 63) == 0) red[t >> 6] = m;
  __syncthreads();
  m = fmaxf(fmaxf(red[0], red[1]), fmaxf(red[2], red[3]));
  float e0 = expf(a - m), e1 = expf(b - m);
  float s = e0 + e1;
#pragma unroll
  for (int o = 1; o < 64; o <<= 1) s += __shfl_xor(s, o);
  if ((t & 63) == 0) red[4 + (t >> 6)] = s;
  __syncthreads();
  s = red[4] + red[5] + red[6] + red[7];
  O[(size_t)r * H + t] = e0 / s;
  O[(size_t)r * H + t + 256] = e1 / s;
}

// ----------------------------- launcher -----------------------------

extern "C" void kernel_launch(void* const* d_in, const int* in_sizes, int n_in,
                              void* d_out, int out_size, void* d_ws, size_t ws_size,
                              hipStream_t stream) {
  (void)in_sizes; (void)n_in;
  const float* embedding = (const float*)d_in[2];
  const float* eWih = (const float*)d_in[3];
  const float* eWhh = (const float*)d_in[4];
  const float* ebih = (const float*)d_in[5];
  const float* ebhh = (const float*)d_in[6];
  const float* eInit = (const float*)d_in[7];
  const float* dWih = (const float*)d_in[8];
  const float* dWhh = (const float*)d_in[9];
  const float* dbih = (const float*)d_in[10];
  const float* dbhh = (const float*)d_in[11];
  const float* dInit = (const float*)d_in[12];
  const float* Wp = (const float*)d_in[13];
  const float* Wo = (const float*)d_in[14];
  float* out = (float*)d_out;
  float* w = (float*)d_ws;

  size_t o = 0;
  float* xW     = w + o; o += (size_t)MZ * GG;
  float* hE     = w + o; o += (size_t)MZ * H;
  float* cE     = w + o; o += (size_t)MZ * H;
  float* ys     = w + o; o += (size_t)SL * MZ * H;     // overlay region A (33.5MB)
  float* alphaA = w + o; o += (size_t)SL * MZ * AR;
  float* betaA  = w + o; o += (size_t)SL * MZ * AR;
  float* hD     = w + o; o += (size_t)RD * H;
  float* cD     = w + o; o += (size_t)RD * H;
  float* regB   = w + o; o += (size_t)RD * GG / 4;     // overlay region B (16.8MB): h1 pair + logits
  float* logits = w + o; o += (size_t)RD * H;
  if (ws_size < o * sizeof(float)) {
    fill_sentinel_r13<<<(out_size + 255) / 256, 256, 0, stream>>>(out, out_size);
    return;
  }

  // overlay A (on ys, dead after params GEMM): sig hi/lo + h0 hi/lo + weights hi/lo + bsum
  unsigned short* sigHi = (unsigned short*)ys;                    // RD*AR
  unsigned short* sigLo = sigHi + (size_t)RD * AR;
  unsigned short* h0Hi  = sigLo + (size_t)RD * AR;                // RD*H
  unsigned short* h0Lo  = h0Hi + (size_t)RD * H;
  unsigned short* WihHi = h0Lo + (size_t)RD * H;                  // GG*AR
  unsigned short* WihLo = WihHi + (size_t)GG * AR;
  unsigned short* WhhHi = WihLo + (size_t)GG * AR;                // GG*H
  unsigned short* WhhLo = WhhHi + (size_t)GG * H;
  float* bsum = (float*)(WhhLo + (size_t)GG * H);                 // GG floats
  // overlay B: second h ping-pong pair
  unsigned short* h1Hi = (unsigned short*)regB;                   // RD*H
  unsigned short* h1Lo = h1Hi + (size_t)RD * H;

  init_states_r13<<<(RD * H) / 256, 256, 0, stream>>>(eInit, dInit, hE, cE, hD, cD);

  // encoder (gates go into logits buffer, RD*H = MZ*GG/... MZ*GG = 1M floats < RD*H 4.2M ✓)
  float* egates = logits;
  gemm_abt_r13<1><<<dim3(GG / 64, MZ / 64), 256, 0, stream>>>(embedding, eWih, xW, ebih, ebhh, MZ, GG, EMB);
  for (int s = 0; s < SL; ++s) {
    gemm_abt_r13<2><<<dim3(GG / 64, MZ / 64), 256, 0, stream>>>(hE, eWhh, egates, xW, nullptr, MZ, GG, H);
    lstm_update_r13<<<(MZ * H) / 256, 256, 0, stream>>>(hE, cE, egates, ys + (size_t)s * MZ * H);
  }

  gemm_ab_r13<1><<<dim3(128 / 64, (SL * MZ) / 64), 256, 0, stream>>>(ys, Wp, alphaA, betaA, SL * MZ, 128, H);

  // ys dead -> build bf16 weights + initial h0 split
  prep_dec_r13<<<(GG * H) / 256, 256, 0, stream>>>(dWih, dWhh, dbih, dbhh,
                                                   WihHi, WihLo, WhhHi, WhhLo, bsum,
                                                   hD, h0Hi, h0Lo);

  for (int s = 0; s < SL; ++s) {
    sample_beta_r13<<<(RD * AR) / 256, 256, 0, stream>>>(alphaA, betaA, sigHi, sigLo, s);
    const unsigned short* hiIn = (s & 1) ? h1Hi : h0Hi;
    const unsigned short* loIn = (s & 1) ? h1Lo : h0Lo;
    unsigned short* hiOut = (s & 1) ? h0Hi : h1Hi;
    unsigned short* loOut = (s & 1) ? h0Lo : h1Lo;
    mfma_lstm_r13<<<dim3(H / 32, RD / 128), 256, 0, stream>>>(
        sigHi, sigLo, hiIn, loIn, WihHi, WihLo, WhhHi, WhhLo, bsum,
        hD, cD, hiOut, loOut, (s == SL - 1) ? 1 : 0);
  }

  gemm_ab_r13<0><<<dim3(H / 64, RD / 64), 256, 0, stream>>>(hD, Wo, logits, nullptr, RD, H, H);
  softmax_rows_r13<<<RD, 256, 0, stream>>>(logits, out);
}